// Round 1
// baseline (4366.194 us; speedup 1.0000x reference)
//
#include <hip/hip_runtime.h>
#include <math.h>

#define Ln 8
#define Bn 2
#define Tn 1024
#define Dm 1024
#define Hn 16
#define Fm 4096
#define Vn 50257
#define NTOK 2048   // B*T

typedef unsigned short u16;
typedef u16   u16x8  __attribute__((ext_vector_type(8)));
typedef __bf16 bf16x8 __attribute__((ext_vector_type(8)));
typedef float f32x4  __attribute__((ext_vector_type(4)));

__device__ __forceinline__ u16 f2bf(float f){
  unsigned u = __builtin_bit_cast(unsigned, f);
  u += 0x7FFFu + ((u >> 16) & 1u);            // RNE
  return (u16)(u >> 16);
}
__device__ __forceinline__ float bf2f(u16 s){
  return __builtin_bit_cast(float, ((unsigned)s) << 16);
}
__device__ __forceinline__ float gelu_f(float v){
  return 0.5f * v * (1.0f + erff(v * 0.70710678118654752440f));
}

// ---------------- embedding: x[b,t,:] = emb[idx[b,t],:] + pos[t,:] ----------------
__global__ __launch_bounds__(256) void embed_kernel(const int* __restrict__ idx,
                                                    const float* __restrict__ emb,
                                                    const float* __restrict__ pos,
                                                    float* __restrict__ x){
  int row = blockIdx.x;                // 0..2047
  int t = row & (Tn - 1);
  int id = idx[row];
  const float4* e = (const float4*)(emb + (size_t)id * Dm);
  const float4* p = (const float4*)(pos + (size_t)t * Dm);
  float4* o = (float4*)(x + (size_t)row * Dm);
  int i = threadIdx.x;                 // Dm/4 = 256
  float4 a = e[i], b = p[i];
  o[i] = make_float4(a.x + b.x, a.y + b.y, a.z + b.z, a.w + b.w);
}

// ---------------- layernorm (f32 in, bf16 out) ----------------
__global__ __launch_bounds__(256) void ln_kernel(const float* __restrict__ xin,
                                                 const float* __restrict__ w,
                                                 const float* __restrict__ bb,
                                                 u16* __restrict__ out){
  int row = blockIdx.x;
  int t = threadIdx.x;
  float4 v = ((const float4*)(xin + (size_t)row * Dm))[t];
  float s  = v.x + v.y + v.z + v.w;
  float s2 = v.x*v.x + v.y*v.y + v.z*v.z + v.w*v.w;
  #pragma unroll
  for (int off = 1; off < 64; off <<= 1){
    s  += __shfl_xor(s, off);
    s2 += __shfl_xor(s2, off);
  }
  __shared__ float red[8];
  int wv = t >> 6, lane = t & 63;
  if (lane == 0){ red[wv] = s; red[4 + wv] = s2; }
  __syncthreads();
  s  = red[0] + red[1] + red[2] + red[3];
  s2 = red[4] + red[5] + red[6] + red[7];
  float mean = s * (1.0f / Dm);
  float var  = s2 * (1.0f / Dm) - mean * mean;
  float rs = rsqrtf(var + 1e-5f);
  float4 wv4 = ((const float4*)w)[t];
  float4 bv4 = ((const float4*)bb)[t];
  u16 o4[4];
  o4[0] = f2bf((v.x - mean) * rs * wv4.x + bv4.x);
  o4[1] = f2bf((v.y - mean) * rs * wv4.y + bv4.y);
  o4[2] = f2bf((v.z - mean) * rs * wv4.z + bv4.z);
  o4[3] = f2bf((v.w - mean) * rs * wv4.w + bv4.w);
  *(uint2*)(out + (size_t)row * Dm + t * 4) = *(uint2*)o4;
}

// ---------------- weight transpose: f32 [K][N] (col slice at c0) -> bf16 [W][K] ----------------
__global__ __launch_bounds__(256) void transpose_w(const float* __restrict__ Bw,
                                                   u16* __restrict__ Bt,
                                                   int N, int K, int c0){
  int n0 = blockIdx.x * 32, k0 = blockIdx.y * 32;
  __shared__ float tile[32][36];
  int t = threadIdx.x;
  int r = t >> 3, ci = t & 7;          // r: 0..31
  #pragma unroll
  for (int u = 0; u < 4; u++){
    int cc = ci + u * 8;
    int gn = c0 + n0 + cc;
    tile[r][cc] = (gn < N) ? Bw[(size_t)(k0 + r) * N + gn] : 0.0f;
  }
  __syncthreads();
  int np = t >> 3, ki = t & 7;
  #pragma unroll
  for (int u = 0; u < 4; u++){
    int kk = ki + u * 8;
    Bt[(size_t)(n0 + np) * K + k0 + kk] = f2bf(tile[kk][np]);
  }
}

// ---------------- GEMM: C[2048][Nout] = A(bf16 [2048][K]) @ Bt(bf16 [N][K])^T ----------------
// MODE 0: out bf16 = v+bias            (qkv)
// MODE 1: out bf16 = gelu(v+bias)      (fc1)
// MODE 2: resid += gelu(v+bias)        (fc2)
// MODE 3: out f32 = v+bias, col guard  (head)
#define BM 128
#define BN 128
#define BK 32
template<int MODE>
__global__ __launch_bounds__(256) void gemm_kernel(const u16* __restrict__ A,
                                                   const u16* __restrict__ Bt,
                                                   const float* __restrict__ bias,
                                                   void* __restrict__ outp,
                                                   float* __restrict__ resid,
                                                   int K, int Nout, int c0){
  __shared__ u16 sA[BM][BK];
  __shared__ u16 sB[BN][BK];
  int t = threadIdx.x;
  int lane = t & 63, wv = t >> 6;
  int wm = wv >> 1, wn = wv & 1;
  int lr = lane & 15, lg = lane >> 4;
  int m0 = blockIdx.y * BM, n0 = blockIdx.x * BN;

  f32x4 acc[4][4] = {};

  int row = t >> 2, kc = (t & 3) * 8;
  for (int k0 = 0; k0 < K; k0 += BK){
    __syncthreads();
    *(int4*)&sA[row][kc]      = *(const int4*)(A  + (size_t)(m0 + row)      * K + k0 + kc);
    *(int4*)&sA[row + 64][kc] = *(const int4*)(A  + (size_t)(m0 + row + 64) * K + k0 + kc);
    *(int4*)&sB[row][kc]      = *(const int4*)(Bt + (size_t)(n0 + row)      * K + k0 + kc);
    *(int4*)&sB[row + 64][kc] = *(const int4*)(Bt + (size_t)(n0 + row + 64) * K + k0 + kc);
    __syncthreads();
    bf16x8 af[4], bfr[4];
    #pragma unroll
    for (int i = 0; i < 4; i++) af[i]  = *(const bf16x8*)&sA[wm*64 + i*16 + lr][lg*8];
    #pragma unroll
    for (int j = 0; j < 4; j++) bfr[j] = *(const bf16x8*)&sB[wn*64 + j*16 + lr][lg*8];
    #pragma unroll
    for (int i = 0; i < 4; i++)
      #pragma unroll
      for (int j = 0; j < 4; j++)
        acc[i][j] = __builtin_amdgcn_mfma_f32_16x16x32_bf16(af[i], bfr[j], acc[i][j], 0, 0, 0);
  }

  #pragma unroll
  for (int i = 0; i < 4; i++){
    int gr0 = m0 + wm*64 + i*16 + lg*4;
    #pragma unroll
    for (int j = 0; j < 4; j++){
      int gc = c0 + n0 + wn*64 + j*16 + lr;
      if (MODE == 3 && gc >= Nout) continue;
      float bb = bias[gc];
      #pragma unroll
      for (int r = 0; r < 4; r++){
        float v = acc[i][j][r] + bb;
        size_t oi = (size_t)(gr0 + r) * Nout + gc;
        if (MODE == 0)      ((u16*)outp)[oi] = f2bf(v);
        else if (MODE == 1) ((u16*)outp)[oi] = f2bf(gelu_f(v));
        else if (MODE == 2) resid[oi] = resid[oi] + gelu_f(v);
        else                ((float*)outp)[oi] = v;
      }
    }
  }
}

// ---------------- fused causal attention (flash-style, f32, adds into x) ----------------
// grid: (B*H, T/64), block 256.  thread = (qr = t>>2, c = t&3); owns dims c*16..c*16+15
__global__ __launch_bounds__(256) void attn_kernel(const u16* __restrict__ qkv,
                                                   float* __restrict__ x){
  int bh = blockIdx.x;
  int b = bh >> 4, h = bh & 15;
  int qt = blockIdx.y;
  int t = threadIdx.x;
  int qr = t >> 2, c = t & 3;
  int tq = qt * 64 + qr;
  int lane = t & 63;
  int lanebase = lane & ~3;

  __shared__ u16 sK[64][64];
  __shared__ u16 sV[64][64];

  const size_t rstr = 3 * Dm;
  const u16* qrow = qkv + (size_t)(b * Tn + tq) * rstr + h * 64;
  float q[64];
  #pragma unroll
  for (int i = 0; i < 8; i++){
    u16x8 raw = *(const u16x8*)(qrow + i * 8);
    #pragma unroll
    for (int u = 0; u < 8; u++) q[i*8+u] = bf2f(raw[u]) * 0.03125f;  // 1/sqrt(1024)
  }

  float o[16];
  #pragma unroll
  for (int u = 0; u < 16; u++) o[u] = 0.0f;
  float m = -INFINITY, lsum = 0.0f;

  for (int kt = 0; kt <= qt; kt++){
    __syncthreads();
    {
      int r = t >> 2, cg = (t & 3) * 16;
      const u16* krow = qkv + (size_t)(b * Tn + kt*64 + r) * rstr + Dm     + h * 64 + cg;
      const u16* vrow = qkv + (size_t)(b * Tn + kt*64 + r) * rstr + 2*Dm   + h * 64 + cg;
      *(int4*)&sK[r][cg]     = *(const int4*)(krow);
      *(int4*)&sK[r][cg + 8] = *(const int4*)(krow + 8);
      *(int4*)&sV[r][cg]     = *(const int4*)(vrow);
      *(int4*)&sV[r][cg + 8] = *(const int4*)(vrow + 8);
    }
    __syncthreads();

    float p[16];
    float tmax = -INFINITY;
    #pragma unroll
    for (int jj = 0; jj < 16; jj++){
      int j = c * 16 + jj;
      float s = 0.0f;
      #pragma unroll
      for (int d8 = 0; d8 < 8; d8++){
        u16x8 kv = *(const u16x8*)&sK[j][d8 * 8];
        #pragma unroll
        for (int u = 0; u < 8; u++) s += q[d8*8+u] * bf2f(kv[u]);
      }
      bool valid = (kt * 64 + j) <= tq;
      p[jj] = valid ? s : -INFINITY;
      tmax = fmaxf(tmax, p[jj]);
    }
    tmax = fmaxf(tmax, __shfl_xor(tmax, 1));
    tmax = fmaxf(tmax, __shfl_xor(tmax, 2));
    float newm = fmaxf(m, tmax);
    float rescale = __expf(m - newm);          // m=-inf first tile -> 0
    float psum = 0.0f;
    #pragma unroll
    for (int jj = 0; jj < 16; jj++){
      float pv = (p[jj] == -INFINITY) ? 0.0f : __expf(p[jj] - newm);
      p[jj] = pv; psum += pv;
    }
    psum += __shfl_xor(psum, 1);
    psum += __shfl_xor(psum, 2);
    lsum = lsum * rescale + psum;
    m = newm;
    #pragma unroll
    for (int u = 0; u < 16; u++) o[u] *= rescale;
    #pragma unroll
    for (int j = 0; j < 64; j++){
      float pj = __shfl(p[j & 15], lanebase + (j >> 4));
      #pragma unroll
      for (int d8 = 0; d8 < 2; d8++){
        u16x8 vv = *(const u16x8*)&sV[j][c * 16 + d8 * 8];
        #pragma unroll
        for (int u = 0; u < 8; u++) o[d8*8+u] += pj * bf2f(vv[u]);
      }
    }
  }
  float inv = 1.0f / lsum;
  float* xr = x + (size_t)(b * Tn + tq) * Dm + h * 64 + c * 16;
  #pragma unroll
  for (int u = 0; u < 16; u++) xr[u] += o[u] * inv;
}

// ---------------- host orchestration ----------------
extern "C" void kernel_launch(void* const* d_in, const int* in_sizes, int n_in,
                              void* d_out, int out_size, void* d_ws, size_t ws_size,
                              hipStream_t stream){
  const int*   idx   = (const int*)  d_in[0];
  const float* emb   = (const float*)d_in[1];
  const float* pos   = (const float*)d_in[2];
  const float* ln1w  = (const float*)d_in[3];
  const float* ln1b  = (const float*)d_in[4];
  const float* qkvw  = (const float*)d_in[5];
  const float* qkvb  = (const float*)d_in[6];
  const float* ln2w  = (const float*)d_in[7];
  const float* ln2b  = (const float*)d_in[8];
  const float* fc1w  = (const float*)d_in[9];
  const float* fc1b  = (const float*)d_in[10];
  const float* fc2w  = (const float*)d_in[11];
  const float* fc2b  = (const float*)d_in[12];
  const float* lnfw  = (const float*)d_in[13];
  const float* lnfb  = (const float*)d_in[14];
  const float* headw = (const float*)d_in[15];
  const float* headb = (const float*)d_in[16];
  float* out = (float*)d_out;

  char* ws = (char*)d_ws;
  float* x   = (float*)(ws);                       // 8 MB  [2048][1024] f32
  u16*   h   = (u16*)  (ws + (8u  << 20));         // 4 MB  [2048][1024] bf16
  u16*   qkv = (u16*)  (ws + (12u << 20));         // 12 MB [2048][3072] bf16
  u16*   f1  = (u16*)  (ws + (24u << 20));         // 16 MB [2048][4096] bf16
  u16*   Bt  = (u16*)  (ws + (40u << 20));         // 16 MB transposed-weight panel

  embed_kernel<<<NTOK, 256, 0, stream>>>(idx, emb, pos, x);

  for (int l = 0; l < Ln; l++){
    // --- attention block ---
    ln_kernel<<<NTOK, 256, 0, stream>>>(x, ln1w + l*Dm, ln1b + l*Dm, h);
    transpose_w<<<dim3(3072/32, Dm/32), 256, 0, stream>>>(qkvw + (size_t)l*Dm*3072, Bt, 3072, Dm, 0);
    gemm_kernel<0><<<dim3(3072/BN, NTOK/BM), 256, 0, stream>>>(h, Bt, qkvb + l*3072, qkv, nullptr, Dm, 3072, 0);
    attn_kernel<<<dim3(Bn*Hn, Tn/64), 256, 0, stream>>>(qkv, x);
    // --- MLP block ---
    ln_kernel<<<NTOK, 256, 0, stream>>>(x, ln2w + l*Dm, ln2b + l*Dm, h);
    transpose_w<<<dim3(Fm/32, Dm/32), 256, 0, stream>>>(fc1w + (size_t)l*Dm*Fm, Bt, Fm, Dm, 0);
    gemm_kernel<1><<<dim3(Fm/BN, NTOK/BM), 256, 0, stream>>>(h, Bt, fc1b + l*Fm, f1, nullptr, Dm, Fm, 0);
    transpose_w<<<dim3(Dm/32, Fm/32), 256, 0, stream>>>(fc2w + (size_t)l*Fm*Dm, Bt, Dm, Fm, 0);
    gemm_kernel<2><<<dim3(Dm/BN, NTOK/BM), 256, 0, stream>>>(f1, Bt, fc2b + l*Dm, nullptr, x, Fm, Dm, 0);
  }

  ln_kernel<<<NTOK, 256, 0, stream>>>(x, lnfw, lnfb, h);

  const int CHUNK = 8192;
  for (int c0 = 0; c0 < Vn; c0 += CHUNK){
    int W = Vn - c0; if (W > CHUNK) W = CHUNK;
    int ngx = (W + BN - 1) / BN;                   // 128-col tiles this chunk
    transpose_w<<<dim3(ngx * 4, Dm/32), 256, 0, stream>>>(headw, Bt, Vn, Dm, c0);
    gemm_kernel<3><<<dim3(ngx, NTOK/BM), 256, 0, stream>>>(h, Bt, headb, out, nullptr, Dm, Vn, c0);
  }
}

// Round 2
// 2453.128 us; speedup vs baseline: 1.7798x; 1.7798x over previous
//
#include <hip/hip_runtime.h>
#include <math.h>

#define Ln 8
#define Bn 2
#define Tn 1024
#define Dm 1024
#define Hn 16
#define Fm 4096
#define Vn 50257
#define NTOK 2048   // B*T

typedef unsigned short u16;
typedef u16   u16x8  __attribute__((ext_vector_type(8)));
typedef __bf16 bf16x8 __attribute__((ext_vector_type(8)));
typedef float f32x4  __attribute__((ext_vector_type(4)));

__device__ __forceinline__ u16 f2bf(float f){
  unsigned u = __builtin_bit_cast(unsigned, f);
  u += 0x7FFFu + ((u >> 16) & 1u);            // RNE
  return (u16)(u >> 16);
}
__device__ __forceinline__ float bf2f(u16 s){
  return __builtin_bit_cast(float, ((unsigned)s) << 16);
}
__device__ __forceinline__ float gelu_f(float v){
  return 0.5f * v * (1.0f + erff(v * 0.70710678118654752440f));
}
__device__ __forceinline__ void gload16(const void* g, void* l){
  __builtin_amdgcn_global_load_lds(
      (const __attribute__((address_space(1))) void*)g,
      (__attribute__((address_space(3))) void*)l, 16, 0, 0);
}

// ---------------- embedding: x[b,t,:] = emb[idx[b,t],:] + pos[t,:] ----------------
__global__ __launch_bounds__(256) void embed_kernel(const int* __restrict__ idx,
                                                    const float* __restrict__ emb,
                                                    const float* __restrict__ pos,
                                                    float* __restrict__ x){
  int row = blockIdx.x;                // 0..2047
  int t = row & (Tn - 1);
  int id = idx[row];
  const float4* e = (const float4*)(emb + (size_t)id * Dm);
  const float4* p = (const float4*)(pos + (size_t)t * Dm);
  float4* o = (float4*)(x + (size_t)row * Dm);
  int i = threadIdx.x;                 // Dm/4 = 256
  float4 a = e[i], b = p[i];
  o[i] = make_float4(a.x + b.x, a.y + b.y, a.z + b.z, a.w + b.w);
}

// ---------------- layernorm (f32 in, bf16 out) ----------------
__global__ __launch_bounds__(256) void ln_kernel(const float* __restrict__ xin,
                                                 const float* __restrict__ w,
                                                 const float* __restrict__ bb,
                                                 u16* __restrict__ out){
  int row = blockIdx.x;
  int t = threadIdx.x;
  float4 v = ((const float4*)(xin + (size_t)row * Dm))[t];
  float s  = v.x + v.y + v.z + v.w;
  float s2 = v.x*v.x + v.y*v.y + v.z*v.z + v.w*v.w;
  #pragma unroll
  for (int off = 1; off < 64; off <<= 1){
    s  += __shfl_xor(s, off);
    s2 += __shfl_xor(s2, off);
  }
  __shared__ float red[8];
  int wv = t >> 6, lane = t & 63;
  if (lane == 0){ red[wv] = s; red[4 + wv] = s2; }
  __syncthreads();
  s  = red[0] + red[1] + red[2] + red[3];
  s2 = red[4] + red[5] + red[6] + red[7];
  float mean = s * (1.0f / Dm);
  float var  = s2 * (1.0f / Dm) - mean * mean;
  float rs = rsqrtf(var + 1e-5f);
  float4 wv4 = ((const float4*)w)[t];
  float4 bv4 = ((const float4*)bb)[t];
  u16 o4[4];
  o4[0] = f2bf((v.x - mean) * rs * wv4.x + bv4.x);
  o4[1] = f2bf((v.y - mean) * rs * wv4.y + bv4.y);
  o4[2] = f2bf((v.z - mean) * rs * wv4.z + bv4.z);
  o4[3] = f2bf((v.w - mean) * rs * wv4.w + bv4.w);
  *(uint2*)(out + (size_t)row * Dm + t * 4) = *(uint2*)o4;
}

// ---------------- weight transpose: f32 [K][N] (col slice at c0) -> bf16 [W][K] ----------------
__global__ __launch_bounds__(256) void transpose_w(const float* __restrict__ Bw,
                                                   u16* __restrict__ Bt,
                                                   int N, int K, int c0){
  int n0 = blockIdx.x * 32, k0 = blockIdx.y * 32;
  __shared__ float tile[32][36];
  int t = threadIdx.x;
  int r = t >> 3, ci = t & 7;          // r: 0..31
  #pragma unroll
  for (int u = 0; u < 4; u++){
    int cc = ci + u * 8;
    int gn = c0 + n0 + cc;
    tile[r][cc] = (gn < N) ? Bw[(size_t)(k0 + r) * N + gn] : 0.0f;
  }
  __syncthreads();
  int np = t >> 3, ki = t & 7;
  #pragma unroll
  for (int u = 0; u < 4; u++){
    int kk = ki + u * 8;
    Bt[(size_t)(n0 + np) * K + k0 + kk] = f2bf(tile[kk][np]);
  }
}

// ---------------- GEMM: C[2048][Nout] = A(bf16 [2048][K]) @ Bt(bf16 [N][K])^T ----------------
// MODE 0: out bf16 = v+bias (qkv); V cols (>=2048) routed transposed into vT
// MODE 1: out bf16 = gelu(v+bias)      (fc1)
// MODE 2: resid += gelu(v+bias)        (fc2)
// MODE 3: out f32 = v+bias, col guard  (head)
#define BM 128
#define BN 128
#define BK 32
template<int MODE>
__global__ __launch_bounds__(256) void gemm_kernel(const u16* __restrict__ A,
                                                   const u16* __restrict__ Bt,
                                                   const float* __restrict__ bias,
                                                   void* __restrict__ outp,
                                                   float* __restrict__ resid,
                                                   u16* __restrict__ vT,
                                                   int K, int Nout, int c0){
  __shared__ u16 sA[BM][BK];
  __shared__ u16 sB[BN][BK];
  int t = threadIdx.x;
  int lane = t & 63, wv = t >> 6;
  int wm = wv >> 1, wn = wv & 1;
  int lr = lane & 15, lg = lane >> 4;
  int m0 = blockIdx.y * BM, n0 = blockIdx.x * BN;

  f32x4 acc[4][4] = {};

  int row = t >> 2, kc = (t & 3) * 8;
  char* ldsA0 = (char*)&sA[0][0]  + (size_t)wv * 1024;   // wave-uniform LDS bases
  char* ldsA1 = (char*)&sA[64][0] + (size_t)wv * 1024;   // lane writes base + lane*16
  char* ldsB0 = (char*)&sB[0][0]  + (size_t)wv * 1024;
  char* ldsB1 = (char*)&sB[64][0] + (size_t)wv * 1024;
  for (int k0 = 0; k0 < K; k0 += BK){
    __syncthreads();
    gload16(A  + (size_t)(m0 + row)      * K + k0 + kc, ldsA0);
    gload16(A  + (size_t)(m0 + row + 64) * K + k0 + kc, ldsA1);
    gload16(Bt + (size_t)(n0 + row)      * K + k0 + kc, ldsB0);
    gload16(Bt + (size_t)(n0 + row + 64) * K + k0 + kc, ldsB1);
    __syncthreads();
    bf16x8 af[4], bfr[4];
    #pragma unroll
    for (int i = 0; i < 4; i++) af[i]  = *(const bf16x8*)&sA[wm*64 + i*16 + lr][lg*8];
    #pragma unroll
    for (int j = 0; j < 4; j++) bfr[j] = *(const bf16x8*)&sB[wn*64 + j*16 + lr][lg*8];
    #pragma unroll
    for (int i = 0; i < 4; i++)
      #pragma unroll
      for (int j = 0; j < 4; j++)
        acc[i][j] = __builtin_amdgcn_mfma_f32_16x16x32_bf16(af[i], bfr[j], acc[i][j], 0, 0, 0);
  }

  #pragma unroll
  for (int i = 0; i < 4; i++){
    int gr0 = m0 + wm*64 + i*16 + lg*4;
    #pragma unroll
    for (int j = 0; j < 4; j++){
      int gc = c0 + n0 + wn*64 + j*16 + lr;
      if (MODE == 3 && gc >= Nout) continue;
      float bb = bias[gc];
      if (MODE == 0 && gc >= 2048){
        // V columns -> vT[(bh*64+d)][t], packed 4 consecutive t per 8B store
        int hh = (gc - 2048) >> 6, dd = (gc - 2048) & 63;
        int b_ = gr0 >> 10, tt = gr0 & 1023;
        u16 pk[4];
        #pragma unroll
        for (int r = 0; r < 4; r++) pk[r] = f2bf(acc[i][j][r] + bb);
        *(uint2*)&vT[((size_t)((b_*Hn + hh)*64 + dd))*Tn + tt] = *(uint2*)pk;
        continue;
      }
      #pragma unroll
      for (int r = 0; r < 4; r++){
        float v = acc[i][j][r] + bb;
        size_t oi = (size_t)(gr0 + r) * Nout + gc;
        if (MODE == 0)      ((u16*)outp)[oi] = f2bf(v);
        else if (MODE == 1) ((u16*)outp)[oi] = f2bf(gelu_f(v));
        else if (MODE == 2) resid[oi] = resid[oi] + gelu_f(v);
        else                ((float*)outp)[oi] = v;
      }
    }
  }
}

// ---------------- MFMA fused causal attention ----------------
// grid (Bn*Hn, Tn/64), block 256 = 4 waves; wave w owns q-rows qt*64 + w*16 .. +15.
// S = Q.K^T via mfma(qf, kfrag): C layout q=(lane>>4)*4+r (local 16), kk=nf*16+(lane&15).
// P re-laid out through wave-private LDS rows; PV B-operand from transposed-V LDS tile.
__global__ __launch_bounds__(256) void attn_mfma(const u16* __restrict__ qkv,
                                                 const u16* __restrict__ vT,
                                                 float* __restrict__ x){
  int bh = blockIdx.x;
  int b = bh >> 4, h_ = bh & 15;
  int qt = blockIdx.y;
  int t = threadIdx.x;
  int w = t >> 6, lane = t & 63;
  int lr = lane & 15, lg = lane >> 4;

  __shared__ u16 sK [64][72];
  __shared__ u16 sVt[64][72];
  __shared__ u16 sP [64][72];

  // Q A-fragments: row = lr (local within wave's 16 rows), k = kf*32 + lg*8
  const u16* qbase = qkv + ((size_t)(b*Tn + qt*64 + w*16 + lr)) * 3*Dm + h_*64 + lg*8;
  bf16x8 qf[2];
  qf[0] = *(const bf16x8*)(qbase);
  qf[1] = *(const bf16x8*)(qbase + 32);

  f32x4 o_[4] = {};                 // O fragments over d-tiles; rows = lg*4+r
  float m_[4], l_[4];
  #pragma unroll
  for (int r = 0; r < 4; r++){ m_[r] = -INFINITY; l_[r] = 0.0f; }

  const float sc = 0.03125f;        // 1/sqrt(D=1024) per reference
  for (int kt = 0; kt <= qt; kt++){
    __syncthreads();
    {
      int r = t >> 2, cg = (t & 3) * 16;
      const u16* krow = qkv + ((size_t)(b*Tn + kt*64 + r)) * 3*Dm + Dm + h_*64 + cg;
      *(int4*)&sK[r][cg]     = *(const int4*)(krow);
      *(int4*)&sK[r][cg + 8] = *(const int4*)(krow + 8);
      const u16* vrow = vT + ((size_t)(bh*64 + r)) * Tn + kt*64 + cg;  // sVt[d][k]
      *(int4*)&sVt[r][cg]     = *(const int4*)(vrow);
      *(int4*)&sVt[r][cg + 8] = *(const int4*)(vrow + 8);
    }
    __syncthreads();

    // S = Q.K^T  (16 q-rows x 64 kk)
    f32x4 s[4] = {};
    #pragma unroll
    for (int kf = 0; kf < 2; kf++){
      #pragma unroll
      for (int nf = 0; nf < 4; nf++){
        bf16x8 kfrag = *(const bf16x8*)&sK[nf*16 + lr][kf*32 + lg*8];
        s[nf] = __builtin_amdgcn_mfma_f32_16x16x32_bf16(qf[kf], kfrag, s[nf], 0, 0, 0);
      }
    }

    // online softmax (per q-row; each lane holds 4 rows, 4 kk-cols each x 4 frags)
    bool lastt = (kt == qt);
    float tmax[4] = {-INFINITY, -INFINITY, -INFINITY, -INFINITY};
    #pragma unroll
    for (int nf = 0; nf < 4; nf++)
      #pragma unroll
      for (int r = 0; r < 4; r++){
        float v = s[nf][r] * sc;
        if (lastt){
          int kkg = nf*16 + lr, qg = w*16 + lg*4 + r;   // same 64-block
          if (kkg > qg) v = -INFINITY;
        }
        s[nf][r] = v;
        tmax[r] = fmaxf(tmax[r], v);
      }
    #pragma unroll
    for (int r = 0; r < 4; r++){
      tmax[r] = fmaxf(tmax[r], __shfl_xor(tmax[r], 1));
      tmax[r] = fmaxf(tmax[r], __shfl_xor(tmax[r], 2));
      tmax[r] = fmaxf(tmax[r], __shfl_xor(tmax[r], 4));
      tmax[r] = fmaxf(tmax[r], __shfl_xor(tmax[r], 8));
    }
    float resc[4], psum[4];
    #pragma unroll
    for (int r = 0; r < 4; r++){
      float nm = fmaxf(m_[r], tmax[r]);
      resc[r] = __expf(m_[r] - nm);
      m_[r] = nm;
      psum[r] = 0.0f;
    }
    #pragma unroll
    for (int nf = 0; nf < 4; nf++)
      #pragma unroll
      for (int r = 0; r < 4; r++){
        float pv = __expf(s[nf][r] - m_[r]);
        s[nf][r] = pv;
        psum[r] += pv;
      }
    #pragma unroll
    for (int r = 0; r < 4; r++){
      psum[r] += __shfl_xor(psum[r], 1);
      psum[r] += __shfl_xor(psum[r], 2);
      psum[r] += __shfl_xor(psum[r], 4);
      psum[r] += __shfl_xor(psum[r], 8);
      l_[r] = l_[r] * resc[r] + psum[r];
    }
    #pragma unroll
    for (int df = 0; df < 4; df++)
      #pragma unroll
      for (int r = 0; r < 4; r++)
        o_[df][r] *= resc[r];

    // P (C-layout) -> LDS -> A-fragments
    #pragma unroll
    for (int nf = 0; nf < 4; nf++)
      #pragma unroll
      for (int r = 0; r < 4; r++)
        sP[w*16 + lg*4 + r][nf*16 + lr] = f2bf(s[nf][r]);
    __syncthreads();

    #pragma unroll
    for (int kf = 0; kf < 2; kf++){
      bf16x8 pfrag = *(const bf16x8*)&sP[w*16 + lr][kf*32 + lg*8];
      #pragma unroll
      for (int df = 0; df < 4; df++){
        bf16x8 vfrag = *(const bf16x8*)&sVt[df*16 + lr][kf*32 + lg*8];
        o_[df] = __builtin_amdgcn_mfma_f32_16x16x32_bf16(pfrag, vfrag, o_[df], 0, 0, 0);
      }
    }
  }

  float inv[4];
  #pragma unroll
  for (int r = 0; r < 4; r++) inv[r] = 1.0f / l_[r];
  #pragma unroll
  for (int df = 0; df < 4; df++)
    #pragma unroll
    for (int r = 0; r < 4; r++){
      float* xr = x + ((size_t)(b*Tn + qt*64 + w*16 + lg*4 + r)) * Dm + h_*64 + df*16 + lr;
      *xr += o_[df][r] * inv[r];
    }
}

// ---------------- host orchestration ----------------
extern "C" void kernel_launch(void* const* d_in, const int* in_sizes, int n_in,
                              void* d_out, int out_size, void* d_ws, size_t ws_size,
                              hipStream_t stream){
  const int*   idx   = (const int*)  d_in[0];
  const float* emb   = (const float*)d_in[1];
  const float* pos   = (const float*)d_in[2];
  const float* ln1w  = (const float*)d_in[3];
  const float* ln1b  = (const float*)d_in[4];
  const float* qkvw  = (const float*)d_in[5];
  const float* qkvb  = (const float*)d_in[6];
  const float* ln2w  = (const float*)d_in[7];
  const float* ln2b  = (const float*)d_in[8];
  const float* fc1w  = (const float*)d_in[9];
  const float* fc1b  = (const float*)d_in[10];
  const float* fc2w  = (const float*)d_in[11];
  const float* fc2b  = (const float*)d_in[12];
  const float* lnfw  = (const float*)d_in[13];
  const float* lnfb  = (const float*)d_in[14];
  const float* headw = (const float*)d_in[15];
  const float* headb = (const float*)d_in[16];
  float* out = (float*)d_out;

  char* ws = (char*)d_ws;
  float* x   = (float*)(ws);                       // 8 MB  [2048][1024] f32
  u16*   h   = (u16*)  (ws + (8u  << 20));         // 4 MB  [2048][1024] bf16
  u16*   qkv = (u16*)  (ws + (12u << 20));         // 12 MB [2048][3072] bf16 (V cols unused)
  u16*   f1  = (u16*)  (ws + (24u << 20));         // 16 MB [2048][4096] bf16
  u16*   Bt  = (u16*)  (ws + (40u << 20));         // 8 MB transposed-weight panel
  u16*   vT  = (u16*)  (ws + (48u << 20));         // 4 MB [32 bh][64 d][1024 t] bf16

  embed_kernel<<<NTOK, 256, 0, stream>>>(idx, emb, pos, x);

  for (int l = 0; l < Ln; l++){
    // --- attention block ---
    ln_kernel<<<NTOK, 256, 0, stream>>>(x, ln1w + l*Dm, ln1b + l*Dm, h);
    transpose_w<<<dim3(3072/32, Dm/32), 256, 0, stream>>>(qkvw + (size_t)l*Dm*3072, Bt, 3072, Dm, 0);
    gemm_kernel<0><<<dim3(3072/BN, NTOK/BM), 256, 0, stream>>>(h, Bt, qkvb + l*3072, qkv, nullptr, vT, Dm, 3072, 0);
    attn_mfma<<<dim3(Bn*Hn, Tn/64), 256, 0, stream>>>(qkv, vT, x);
    // --- MLP block ---
    ln_kernel<<<NTOK, 256, 0, stream>>>(x, ln2w + l*Dm, ln2b + l*Dm, h);
    transpose_w<<<dim3(Fm/32, Dm/32), 256, 0, stream>>>(fc1w + (size_t)l*Dm*Fm, Bt, Fm, Dm, 0);
    gemm_kernel<1><<<dim3(Fm/BN, NTOK/BM), 256, 0, stream>>>(h, Bt, fc1b + l*Fm, f1, nullptr, nullptr, Dm, Fm, 0);
    transpose_w<<<dim3(Dm/32, Fm/32), 256, 0, stream>>>(fc2w + (size_t)l*Fm*Dm, Bt, Dm, Fm, 0);
    gemm_kernel<2><<<dim3(Dm/BN, NTOK/BM), 256, 0, stream>>>(f1, Bt, fc2b + l*Dm, nullptr, x, nullptr, Fm, Dm, 0);
  }

  ln_kernel<<<NTOK, 256, 0, stream>>>(x, lnfw, lnfb, h);

  const int CHUNK = 4096;
  for (int c0 = 0; c0 < Vn; c0 += CHUNK){
    int W = Vn - c0; if (W > CHUNK) W = CHUNK;
    int ngx = (W + BN - 1) / BN;                   // 128-col tiles this chunk
    transpose_w<<<dim3(ngx * 4, Dm/32), 256, 0, stream>>>(headw, Bt, Vn, Dm, c0);
    gemm_kernel<3><<<dim3(ngx, NTOK/BM), 256, 0, stream>>>(h, Bt, headb, out, nullptr, nullptr, Dm, Vn, c0);
  }
}

// Round 3
// 2143.877 us; speedup vs baseline: 2.0366x; 1.1442x over previous
//
#include <hip/hip_runtime.h>
#include <math.h>

#define Ln 8
#define Bn 2
#define Tn 1024
#define Dm 1024
#define Hn 16
#define Fm 4096
#define Vn 50257
#define NTOK 2048   // B*T

typedef unsigned short u16;
typedef u16   u16x8  __attribute__((ext_vector_type(8)));
typedef __bf16 bf16x8 __attribute__((ext_vector_type(8)));
typedef float f32x4  __attribute__((ext_vector_type(4)));

__device__ __forceinline__ u16 f2bf(float f){
  unsigned u = __builtin_bit_cast(unsigned, f);
  u += 0x7FFFu + ((u >> 16) & 1u);            // RNE
  return (u16)(u >> 16);
}
__device__ __forceinline__ float bf2f(u16 s){
  return __builtin_bit_cast(float, ((unsigned)s) << 16);
}
__device__ __forceinline__ float gelu_f(float v){
  return 0.5f * v * (1.0f + erff(v * 0.70710678118654752440f));
}
__device__ __forceinline__ void gload16(const void* g, void* l){
  __builtin_amdgcn_global_load_lds(
      (const __attribute__((address_space(1))) void*)g,
      (__attribute__((address_space(3))) void*)l, 16, 0, 0);
}

// ---------------- embedding ----------------
__global__ __launch_bounds__(256) void embed_kernel(const int* __restrict__ idx,
                                                    const float* __restrict__ emb,
                                                    const float* __restrict__ pos,
                                                    float* __restrict__ x){
  int row = blockIdx.x;
  int t = row & (Tn - 1);
  int id = idx[row];
  const float4* e = (const float4*)(emb + (size_t)id * Dm);
  const float4* p = (const float4*)(pos + (size_t)t * Dm);
  float4* o = (float4*)(x + (size_t)row * Dm);
  int i = threadIdx.x;
  float4 a = e[i], b = p[i];
  o[i] = make_float4(a.x + b.x, a.y + b.y, a.z + b.z, a.w + b.w);
}

// ---------------- layernorm (f32 in, bf16 out) ----------------
__global__ __launch_bounds__(256) void ln_kernel(const float* __restrict__ xin,
                                                 const float* __restrict__ w,
                                                 const float* __restrict__ bb,
                                                 u16* __restrict__ out){
  int row = blockIdx.x;
  int t = threadIdx.x;
  float4 v = ((const float4*)(xin + (size_t)row * Dm))[t];
  float s  = v.x + v.y + v.z + v.w;
  float s2 = v.x*v.x + v.y*v.y + v.z*v.z + v.w*v.w;
  #pragma unroll
  for (int off = 1; off < 64; off <<= 1){
    s  += __shfl_xor(s, off);
    s2 += __shfl_xor(s2, off);
  }
  __shared__ float red[8];
  int wv = t >> 6, lane = t & 63;
  if (lane == 0){ red[wv] = s; red[4 + wv] = s2; }
  __syncthreads();
  s  = red[0] + red[1] + red[2] + red[3];
  s2 = red[4] + red[5] + red[6] + red[7];
  float mean = s * (1.0f / Dm);
  float var  = s2 * (1.0f / Dm) - mean * mean;
  float rs = rsqrtf(var + 1e-5f);
  float4 wv4 = ((const float4*)w)[t];
  float4 bv4 = ((const float4*)bb)[t];
  u16 o4[4];
  o4[0] = f2bf((v.x - mean) * rs * wv4.x + bv4.x);
  o4[1] = f2bf((v.y - mean) * rs * wv4.y + bv4.y);
  o4[2] = f2bf((v.z - mean) * rs * wv4.z + bv4.z);
  o4[3] = f2bf((v.w - mean) * rs * wv4.w + bv4.w);
  *(uint2*)(out + (size_t)row * Dm + t * 4) = *(uint2*)o4;
}

// ---------------- weight transpose: f32 [K][N] (cols c0+) -> bf16 [n][K], 64x64 tiles ----------------
__global__ __launch_bounds__(256) void transpose_w(const float* __restrict__ Bw,
                                                   u16* __restrict__ Bt,
                                                   int N, int K, int c0){
  int n0 = blockIdx.x * 64, k0 = blockIdx.y * 64;
  __shared__ float tile[64][66];
  int t = threadIdx.x;
  // read: 16 lanes x float4 = full 256B row segment, 4 rows/wave/pass
  int rr = t >> 4, nc = (t & 15) * 4;
  #pragma unroll
  for (int u = 0; u < 4; u++){
    int kk = rr + u * 16;
    int gn = c0 + n0 + nc;
    const float* src = Bw + (size_t)(k0 + kk) * N;
    float4 v;
    if (gn + 3 < N) v = *(const float4*)(src + gn);
    else {
      v.x = (gn     < N) ? src[gn]     : 0.0f;
      v.y = (gn + 1 < N) ? src[gn + 1] : 0.0f;
      v.z = (gn + 2 < N) ? src[gn + 2] : 0.0f;
      v.w = (gn + 3 < N) ? src[gn + 3] : 0.0f;
    }
    tile[kk][nc]     = v.x;
    tile[kk][nc + 1] = v.y;
    tile[kk][nc + 2] = v.z;
    tile[kk][nc + 3] = v.w;
  }
  __syncthreads();
  // write: thread owns row np, k-bytes [c*16, c*16+16) and +64: int4 coalesced
  int np = t >> 2, c = t & 3;
  u16* dst = Bt + (size_t)(n0 + np) * K + k0;
  u16 pk[8];
  #pragma unroll
  for (int j = 0; j < 8; j++) pk[j] = f2bf(tile[c*8 + j][np]);
  *(int4*)(dst + c*8) = *(int4*)pk;
  #pragma unroll
  for (int j = 0; j < 8; j++) pk[j] = f2bf(tile[32 + c*8 + j][np]);
  *(int4*)(dst + 32 + c*8) = *(int4*)pk;
}

// ---------------- GEMM: C[2048][Nout] = A(bf16 [2048][K]) @ Bt(bf16 [N][K])^T ----------------
// BK=64, both-sides XOR swizzle: LDS[row][col] holds logical [row][col ^ ((row>>2&3)<<4)]
// MODE 0: out bf16 = v+bias (qkv); V cols (>=2048) routed transposed into vT
// MODE 1: out bf16 = gelu(v+bias)      (fc1)
// MODE 2: resid += gelu(v+bias)        (fc2)
// MODE 3: out f32 = v+bias, col guard  (head)
#define BM 128
#define BN 128
template<int MODE>
__global__ __launch_bounds__(256) void gemm_kernel(const u16* __restrict__ A,
                                                   const u16* __restrict__ Bt,
                                                   const float* __restrict__ bias,
                                                   void* __restrict__ outp,
                                                   float* __restrict__ resid,
                                                   u16* __restrict__ vT,
                                                   int K, int Nout, int c0){
  __shared__ u16 sA[128][64];
  __shared__ u16 sB[128][64];
  int t = threadIdx.x;
  int lane = t & 63, w = t >> 6;
  int wm = w >> 1, wn = w & 1;
  int lr = lane & 15, lg = lane >> 4;
  int m0 = blockIdx.y * BM, n0 = blockIdx.x * BN;

  f32x4 acc[4][4] = {};

  int srow = lane >> 3, scol = (lane & 7) * 8;
  int cswz = ((lr >> 2) & 3) << 4;

  for (int k0 = 0; k0 < K; k0 += 64){
    __syncthreads();
    #pragma unroll
    for (int i = 0; i < 4; i++){
      int rbase = i*32 + w*8;
      int r = rbase + srow;
      int gc = scol ^ (((r >> 2) & 3) << 4);     // pre-swizzled global source (m173)
      gload16(A  + (size_t)(m0 + r) * K + k0 + gc, (char*)&sA[rbase][0]);
      gload16(Bt + (size_t)(n0 + r) * K + k0 + gc, (char*)&sB[rbase][0]);
    }
    __syncthreads();
    #pragma unroll
    for (int kk = 0; kk < 2; kk++){
      bf16x8 af[4], bfr[4];
      #pragma unroll
      for (int i = 0; i < 4; i++) af[i]  = *(const bf16x8*)&sA[wm*64 + i*16 + lr][(kk*32 + lg*8) ^ cswz];
      #pragma unroll
      for (int j = 0; j < 4; j++) bfr[j] = *(const bf16x8*)&sB[wn*64 + j*16 + lr][(kk*32 + lg*8) ^ cswz];
      #pragma unroll
      for (int i = 0; i < 4; i++)
        #pragma unroll
        for (int j = 0; j < 4; j++)
          acc[i][j] = __builtin_amdgcn_mfma_f32_16x16x32_bf16(af[i], bfr[j], acc[i][j], 0, 0, 0);
    }
  }

  #pragma unroll
  for (int i = 0; i < 4; i++){
    int gr0 = m0 + wm*64 + i*16 + lg*4;
    #pragma unroll
    for (int j = 0; j < 4; j++){
      int gc = c0 + n0 + wn*64 + j*16 + lr;
      if (MODE == 3 && gc >= Nout) continue;
      float bb = bias[gc];
      if (MODE == 0 && gc >= 2048){
        int hh = (gc - 2048) >> 6, dd = (gc - 2048) & 63;
        int b_ = gr0 >> 10, tt = gr0 & 1023;
        u16 pk[4];
        #pragma unroll
        for (int r = 0; r < 4; r++) pk[r] = f2bf(acc[i][j][r] + bb);
        *(uint2*)&vT[((size_t)((b_*Hn + hh)*64 + dd))*Tn + tt] = *(uint2*)pk;
        continue;
      }
      #pragma unroll
      for (int r = 0; r < 4; r++){
        float v = acc[i][j][r] + bb;
        size_t oi = (size_t)(gr0 + r) * Nout + gc;
        if (MODE == 0)      ((u16*)outp)[oi] = f2bf(v);
        else if (MODE == 1) ((u16*)outp)[oi] = f2bf(gelu_f(v));
        else if (MODE == 2) resid[oi] = resid[oi] + gelu_f(v);
        else                ((float*)outp)[oi] = v;
      }
    }
  }
}

// ---------------- MFMA fused causal attention (double-buffered K/V, T14 staging) ----------------
// grid (Bn*Hn, Tn/64), block 256 = 4 waves; wave w owns q-rows qt*64 + w*16 .. +15.
__global__ __launch_bounds__(256) void attn_mfma(const u16* __restrict__ qkv,
                                                 const u16* __restrict__ vT,
                                                 float* __restrict__ x){
  int bh = blockIdx.x;
  int b = bh >> 4, h_ = bh & 15;
  int qt = blockIdx.y;
  int t = threadIdx.x;
  int w = t >> 6, lane = t & 63;
  int lr = lane & 15, lg = lane >> 4;

  __shared__ u16 sK [2][64][72];
  __shared__ u16 sVt[2][64][72];
  __shared__ u16 sP [64][72];      // wave-private rows: no cross-wave access

  const u16* qbase = qkv + ((size_t)(b*Tn + qt*64 + w*16 + lr)) * 3*Dm + h_*64 + lg*8;
  bf16x8 qf[2];
  qf[0] = *(const bf16x8*)(qbase);
  qf[1] = *(const bf16x8*)(qbase + 32);

  f32x4 o_[4] = {};
  float m_[4], l_[4];
  #pragma unroll
  for (int r = 0; r < 4; r++){ m_[r] = -INFINITY; l_[r] = 0.0f; }

  // staging lanes: row sr (64 rows), 32B chunk at col sc
  int sr = t >> 2, sc = (t & 3) * 16;
  const u16* kbase = qkv + ((size_t)(b*Tn + sr)) * 3*Dm + Dm + h_*64 + sc;  // advance kt*64*3*Dm
  const u16* vbase = vT + ((size_t)(bh*64 + sr)) * Tn + sc;                 // advance kt*64
  int4 kr0, kr1, vr0, vr1;

  // prologue: stage tile 0 into buffer 0
  kr0 = *(const int4*)(kbase);     kr1 = *(const int4*)(kbase + 8);
  vr0 = *(const int4*)(vbase);     vr1 = *(const int4*)(vbase + 8);
  *(int4*)&sK [0][sr][sc]     = kr0;  *(int4*)&sK [0][sr][sc + 8] = kr1;
  *(int4*)&sVt[0][sr][sc]     = vr0;  *(int4*)&sVt[0][sr][sc + 8] = vr1;

  const float sc_ = 0.03125f;      // 1/sqrt(D=1024) per reference
  for (int kt = 0; kt <= qt; kt++){
    int cur = kt & 1;
    if (kt < qt){                  // T14: issue next tile's loads before compute
      const u16* kb = kbase + (size_t)(kt + 1) * 64 * 3 * Dm;
      const u16* vb = vbase + (kt + 1) * 64;
      kr0 = *(const int4*)(kb);    kr1 = *(const int4*)(kb + 8);
      vr0 = *(const int4*)(vb);    vr1 = *(const int4*)(vb + 8);
    }
    __syncthreads();               // buffer[cur] writes (prev iter) visible

    // S = Q.K^T
    f32x4 s[4] = {};
    #pragma unroll
    for (int kf = 0; kf < 2; kf++){
      #pragma unroll
      for (int nf = 0; nf < 4; nf++){
        bf16x8 kfrag = *(const bf16x8*)&sK[cur][nf*16 + lr][kf*32 + lg*8];
        s[nf] = __builtin_amdgcn_mfma_f32_16x16x32_bf16(qf[kf], kfrag, s[nf], 0, 0, 0);
      }
    }

    bool lastt = (kt == qt);
    float tmax[4] = {-INFINITY, -INFINITY, -INFINITY, -INFINITY};
    #pragma unroll
    for (int nf = 0; nf < 4; nf++)
      #pragma unroll
      for (int r = 0; r < 4; r++){
        float v = s[nf][r] * sc_;
        if (lastt){
          int kkg = nf*16 + lr, qg = w*16 + lg*4 + r;
          if (kkg > qg) v = -INFINITY;
        }
        s[nf][r] = v;
        tmax[r] = fmaxf(tmax[r], v);
      }
    #pragma unroll
    for (int r = 0; r < 4; r++){
      tmax[r] = fmaxf(tmax[r], __shfl_xor(tmax[r], 1));
      tmax[r] = fmaxf(tmax[r], __shfl_xor(tmax[r], 2));
      tmax[r] = fmaxf(tmax[r], __shfl_xor(tmax[r], 4));
      tmax[r] = fmaxf(tmax[r], __shfl_xor(tmax[r], 8));
    }
    float resc[4], psum[4];
    #pragma unroll
    for (int r = 0; r < 4; r++){
      float nm = fmaxf(m_[r], tmax[r]);
      resc[r] = __expf(m_[r] - nm);
      m_[r] = nm;
      psum[r] = 0.0f;
    }
    #pragma unroll
    for (int nf = 0; nf < 4; nf++)
      #pragma unroll
      for (int r = 0; r < 4; r++){
        float pv = __expf(s[nf][r] - m_[r]);
        s[nf][r] = pv;
        psum[r] += pv;
      }
    #pragma unroll
    for (int r = 0; r < 4; r++){
      psum[r] += __shfl_xor(psum[r], 1);
      psum[r] += __shfl_xor(psum[r], 2);
      psum[r] += __shfl_xor(psum[r], 4);
      psum[r] += __shfl_xor(psum[r], 8);
      l_[r] = l_[r] * resc[r] + psum[r];
    }
    #pragma unroll
    for (int df = 0; df < 4; df++)
      #pragma unroll
      for (int r = 0; r < 4; r++)
        o_[df][r] *= resc[r];

    // P C-frag -> wave-private LDS rows -> A-frag (no barrier: wave-local)
    #pragma unroll
    for (int nf = 0; nf < 4; nf++)
      #pragma unroll
      for (int r = 0; r < 4; r++)
        sP[w*16 + lg*4 + r][nf*16 + lr] = f2bf(s[nf][r]);

    #pragma unroll
    for (int kf = 0; kf < 2; kf++){
      bf16x8 pfrag = *(const bf16x8*)&sP[w*16 + lr][kf*32 + lg*8];
      #pragma unroll
      for (int df = 0; df < 4; df++){
        bf16x8 vfrag = *(const bf16x8*)&sVt[cur][df*16 + lr][kf*32 + lg*8];
        o_[df] = __builtin_amdgcn_mfma_f32_16x16x32_bf16(pfrag, vfrag, o_[df], 0, 0, 0);
      }
    }

    if (kt < qt){                  // write-late: land next tile in the other buffer
      int nxt = cur ^ 1;
      *(int4*)&sK [nxt][sr][sc]     = kr0;  *(int4*)&sK [nxt][sr][sc + 8] = kr1;
      *(int4*)&sVt[nxt][sr][sc]     = vr0;  *(int4*)&sVt[nxt][sr][sc + 8] = vr1;
    }
  }

  float inv[4];
  #pragma unroll
  for (int r = 0; r < 4; r++) inv[r] = 1.0f / l_[r];
  #pragma unroll
  for (int df = 0; df < 4; df++)
    #pragma unroll
    for (int r = 0; r < 4; r++){
      float* xr = x + ((size_t)(b*Tn + qt*64 + w*16 + lg*4 + r)) * Dm + h_*64 + df*16 + lr;
      *xr += o_[df][r] * inv[r];
    }
}

// ---------------- host orchestration ----------------
extern "C" void kernel_launch(void* const* d_in, const int* in_sizes, int n_in,
                              void* d_out, int out_size, void* d_ws, size_t ws_size,
                              hipStream_t stream){
  const int*   idx   = (const int*)  d_in[0];
  const float* emb   = (const float*)d_in[1];
  const float* pos   = (const float*)d_in[2];
  const float* ln1w  = (const float*)d_in[3];
  const float* ln1b  = (const float*)d_in[4];
  const float* qkvw  = (const float*)d_in[5];
  const float* qkvb  = (const float*)d_in[6];
  const float* ln2w  = (const float*)d_in[7];
  const float* ln2b  = (const float*)d_in[8];
  const float* fc1w  = (const float*)d_in[9];
  const float* fc1b  = (const float*)d_in[10];
  const float* fc2w  = (const float*)d_in[11];
  const float* fc2b  = (const float*)d_in[12];
  const float* lnfw  = (const float*)d_in[13];
  const float* lnfb  = (const float*)d_in[14];
  const float* headw = (const float*)d_in[15];
  const float* headb = (const float*)d_in[16];
  float* out = (float*)d_out;

  char* ws = (char*)d_ws;
  float* x   = (float*)(ws);                       // 8 MB  [2048][1024] f32
  u16*   h   = (u16*)  (ws + (8u  << 20));         // 4 MB  [2048][1024] bf16
  u16*   qkv = (u16*)  (ws + (12u << 20));         // 12 MB [2048][3072] bf16
  u16*   f1  = (u16*)  (ws + (24u << 20));         // 16 MB [2048][4096] bf16
  u16*   Bt  = (u16*)  (ws + (40u << 20));         // 8 MB transposed-weight panel
  u16*   vT  = (u16*)  (ws + (48u << 20));         // 4 MB [32 bh][64 d][1024 t] bf16

  embed_kernel<<<NTOK, 256, 0, stream>>>(idx, emb, pos, x);

  for (int l = 0; l < Ln; l++){
    // --- attention block ---
    ln_kernel<<<NTOK, 256, 0, stream>>>(x, ln1w + l*Dm, ln1b + l*Dm, h);
    transpose_w<<<dim3(3072/64, Dm/64), 256, 0, stream>>>(qkvw + (size_t)l*Dm*3072, Bt, 3072, Dm, 0);
    gemm_kernel<0><<<dim3(3072/BN, NTOK/BM), 256, 0, stream>>>(h, Bt, qkvb + l*3072, qkv, nullptr, vT, Dm, 3072, 0);
    attn_mfma<<<dim3(Bn*Hn, Tn/64), 256, 0, stream>>>(qkv, vT, x);
    // --- MLP block ---
    ln_kernel<<<NTOK, 256, 0, stream>>>(x, ln2w + l*Dm, ln2b + l*Dm, h);
    transpose_w<<<dim3(Fm/64, Dm/64), 256, 0, stream>>>(fc1w + (size_t)l*Dm*Fm, Bt, Fm, Dm, 0);
    gemm_kernel<1><<<dim3(Fm/BN, NTOK/BM), 256, 0, stream>>>(h, Bt, fc1b + l*Fm, f1, nullptr, nullptr, Dm, Fm, 0);
    transpose_w<<<dim3(Dm/64, Fm/64), 256, 0, stream>>>(fc2w + (size_t)l*Fm*Dm, Bt, Dm, Fm, 0);
    gemm_kernel<2><<<dim3(Dm/BN, NTOK/BM), 256, 0, stream>>>(f1, Bt, fc2b + l*Dm, nullptr, x, nullptr, Fm, Dm, 0);
  }

  ln_kernel<<<NTOK, 256, 0, stream>>>(x, lnfw, lnfb, h);

  const int CHUNK = 4096;
  for (int c0 = 0; c0 < Vn; c0 += CHUNK){
    int W = Vn - c0; if (W > CHUNK) W = CHUNK;
    int ngx = (W + BN - 1) / BN;                   // 128-col gemm tiles this chunk
    transpose_w<<<dim3(ngx * 2, Dm/64), 256, 0, stream>>>(headw, Bt, Vn, Dm, c0);
    gemm_kernel<3><<<dim3(ngx, NTOK/BM), 256, 0, stream>>>(h, Bt, headb, out, nullptr, nullptr, Dm, Vn, c0);
  }
}

// Round 4
// 1999.776 us; speedup vs baseline: 2.1833x; 1.0721x over previous
//
#include <hip/hip_runtime.h>
#include <math.h>

#define Ln 8
#define Bn 2
#define Tn 1024
#define Dm 1024
#define Hn 16
#define Fm 4096
#define Vn 50257
#define NTOK 2048   // B*T

typedef unsigned short u16;
typedef u16   u16x8  __attribute__((ext_vector_type(8)));
typedef __bf16 bf16x8 __attribute__((ext_vector_type(8)));
typedef float f32x4  __attribute__((ext_vector_type(4)));

__device__ __forceinline__ u16 f2bf(float f){
  unsigned u = __builtin_bit_cast(unsigned, f);
  u += 0x7FFFu + ((u >> 16) & 1u);            // RNE
  return (u16)(u >> 16);
}
__device__ __forceinline__ float bf2f(u16 s){
  return __builtin_bit_cast(float, ((unsigned)s) << 16);
}
__device__ __forceinline__ float gelu_f(float v){
  return 0.5f * v * (1.0f + erff(v * 0.70710678118654752440f));
}
__device__ __forceinline__ void gload16(const void* g, void* l){
  __builtin_amdgcn_global_load_lds(
      (const __attribute__((address_space(1))) void*)g,
      (__attribute__((address_space(3))) void*)l, 16, 0, 0);
}

// ---------------- embedding ----------------
__global__ __launch_bounds__(256) void embed_kernel(const int* __restrict__ idx,
                                                    const float* __restrict__ emb,
                                                    const float* __restrict__ pos,
                                                    float* __restrict__ x){
  int row = blockIdx.x;
  int t = row & (Tn - 1);
  int id = idx[row];
  const float4* e = (const float4*)(emb + (size_t)id * Dm);
  const float4* p = (const float4*)(pos + (size_t)t * Dm);
  float4* o = (float4*)(x + (size_t)row * Dm);
  int i = threadIdx.x;
  float4 a = e[i], b = p[i];
  o[i] = make_float4(a.x + b.x, a.y + b.y, a.z + b.z, a.w + b.w);
}

// ---------------- layernorm (f32 in, bf16 out) ----------------
__global__ __launch_bounds__(256) void ln_kernel(const float* __restrict__ xin,
                                                 const float* __restrict__ w,
                                                 const float* __restrict__ bb,
                                                 u16* __restrict__ out){
  int row = blockIdx.x;
  int t = threadIdx.x;
  float4 v = ((const float4*)(xin + (size_t)row * Dm))[t];
  float s  = v.x + v.y + v.z + v.w;
  float s2 = v.x*v.x + v.y*v.y + v.z*v.z + v.w*v.w;
  #pragma unroll
  for (int off = 1; off < 64; off <<= 1){
    s  += __shfl_xor(s, off);
    s2 += __shfl_xor(s2, off);
  }
  __shared__ float red[8];
  int wv = t >> 6, lane = t & 63;
  if (lane == 0){ red[wv] = s; red[4 + wv] = s2; }
  __syncthreads();
  s  = red[0] + red[1] + red[2] + red[3];
  s2 = red[4] + red[5] + red[6] + red[7];
  float mean = s * (1.0f / Dm);
  float var  = s2 * (1.0f / Dm) - mean * mean;
  float rs = rsqrtf(var + 1e-5f);
  float4 wv4 = ((const float4*)w)[t];
  float4 bv4 = ((const float4*)bb)[t];
  u16 o4[4];
  o4[0] = f2bf((v.x - mean) * rs * wv4.x + bv4.x);
  o4[1] = f2bf((v.y - mean) * rs * wv4.y + bv4.y);
  o4[2] = f2bf((v.z - mean) * rs * wv4.z + bv4.z);
  o4[3] = f2bf((v.w - mean) * rs * wv4.w + bv4.w);
  *(uint2*)(out + (size_t)row * Dm + t * 4) = *(uint2*)o4;
}

// ---------------- weight transpose: f32 [K][N] (cols c0+) -> bf16 [n][K], 64x64 tiles ----------------
__global__ __launch_bounds__(256) void transpose_w(const float* __restrict__ Bw,
                                                   u16* __restrict__ Bt,
                                                   int N, int K, int c0){
  int n0 = blockIdx.x * 64, k0 = blockIdx.y * 64;
  __shared__ float tile[64][66];
  int t = threadIdx.x;
  int rr = t >> 4, nc = (t & 15) * 4;
  #pragma unroll
  for (int u = 0; u < 4; u++){
    int kk = rr + u * 16;
    int gn = c0 + n0 + nc;
    const float* src = Bw + (size_t)(k0 + kk) * N;
    float4 v;
    if (gn + 3 < N) v = *(const float4*)(src + gn);
    else {
      v.x = (gn     < N) ? src[gn]     : 0.0f;
      v.y = (gn + 1 < N) ? src[gn + 1] : 0.0f;
      v.z = (gn + 2 < N) ? src[gn + 2] : 0.0f;
      v.w = (gn + 3 < N) ? src[gn + 3] : 0.0f;
    }
    tile[kk][nc]     = v.x;
    tile[kk][nc + 1] = v.y;
    tile[kk][nc + 2] = v.z;
    tile[kk][nc + 3] = v.w;
  }
  __syncthreads();
  int np = t >> 2, c = t & 3;
  u16* dst = Bt + (size_t)(n0 + np) * K + k0;
  u16 pk[8];
  #pragma unroll
  for (int j = 0; j < 8; j++) pk[j] = f2bf(tile[c*8 + j][np]);
  *(int4*)(dst + c*8) = *(int4*)pk;
  #pragma unroll
  for (int j = 0; j < 8; j++) pk[j] = f2bf(tile[32 + c*8 + j][np]);
  *(int4*)(dst + 32 + c*8) = *(int4*)pk;
}

// ---------------- GEMM: C[2048][Nout] = A(bf16 [2048][K]) @ Bt(bf16 [N][K])^T ----------------
#define BM 128
#define BN 128
template<int MODE>
__global__ __launch_bounds__(256) void gemm_kernel(const u16* __restrict__ A,
                                                   const u16* __restrict__ Bt,
                                                   const float* __restrict__ bias,
                                                   void* __restrict__ outp,
                                                   float* __restrict__ resid,
                                                   u16* __restrict__ vT,
                                                   int K, int Nout, int c0){
  __shared__ u16 sA[128][64];
  __shared__ u16 sB[128][64];
  int t = threadIdx.x;
  int lane = t & 63, w = t >> 6;
  int wm = w >> 1, wn = w & 1;
  int lr = lane & 15, lg = lane >> 4;
  int m0 = blockIdx.y * BM, n0 = blockIdx.x * BN;

  f32x4 acc[4][4] = {};

  int srow = lane >> 3, scol = (lane & 7) * 8;
  int cswz = ((lr >> 2) & 3) << 4;

  for (int k0 = 0; k0 < K; k0 += 64){
    __syncthreads();
    #pragma unroll
    for (int i = 0; i < 4; i++){
      int rbase = i*32 + w*8;
      int r = rbase + srow;
      int gc = scol ^ (((r >> 2) & 3) << 4);     // pre-swizzled global source (m173)
      gload16(A  + (size_t)(m0 + r) * K + k0 + gc, (char*)&sA[rbase][0]);
      gload16(Bt + (size_t)(n0 + r) * K + k0 + gc, (char*)&sB[rbase][0]);
    }
    __syncthreads();
    #pragma unroll
    for (int kk = 0; kk < 2; kk++){
      bf16x8 af[4], bfr[4];
      #pragma unroll
      for (int i = 0; i < 4; i++) af[i]  = *(const bf16x8*)&sA[wm*64 + i*16 + lr][(kk*32 + lg*8) ^ cswz];
      #pragma unroll
      for (int j = 0; j < 4; j++) bfr[j] = *(const bf16x8*)&sB[wn*64 + j*16 + lr][(kk*32 + lg*8) ^ cswz];
      #pragma unroll
      for (int i = 0; i < 4; i++)
        #pragma unroll
        for (int j = 0; j < 4; j++)
          acc[i][j] = __builtin_amdgcn_mfma_f32_16x16x32_bf16(af[i], bfr[j], acc[i][j], 0, 0, 0);
    }
  }

  #pragma unroll
  for (int i = 0; i < 4; i++){
    int gr0 = m0 + wm*64 + i*16 + lg*4;
    #pragma unroll
    for (int j = 0; j < 4; j++){
      int gc = c0 + n0 + wn*64 + j*16 + lr;
      if (MODE == 3 && gc >= Nout) continue;
      float bb = bias[gc];
      if (MODE == 0 && gc >= 2048){
        int hh = (gc - 2048) >> 6, dd = (gc - 2048) & 63;
        int b_ = gr0 >> 10, tt = gr0 & 1023;
        u16 pk[4];
        #pragma unroll
        for (int r = 0; r < 4; r++) pk[r] = f2bf(acc[i][j][r] + bb);
        *(uint2*)&vT[((size_t)((b_*Hn + hh)*64 + dd))*Tn + tt] = *(uint2*)pk;
        continue;
      }
      #pragma unroll
      for (int r = 0; r < 4; r++){
        float v = acc[i][j][r] + bb;
        size_t oi = (size_t)(gr0 + r) * Nout + gc;
        if (MODE == 0)      ((u16*)outp)[oi] = f2bf(v);
        else if (MODE == 1) ((u16*)outp)[oi] = f2bf(gelu_f(v));
        else if (MODE == 2) resid[oi] = resid[oi] + gelu_f(v);
        else                ((float*)outp)[oi] = v;
      }
    }
  }
}

// ---------------- MFMA fused causal attention (double-buffered K/V, T14 staging) ----------------
// 1D grid 512; bh = bid&31; j = bid>>5; qt = j<8 ? 15-j : j-8  (heavy-first, paired load balance)
__global__ __launch_bounds__(256) void attn_mfma(const u16* __restrict__ qkv,
                                                 const u16* __restrict__ vT,
                                                 float* __restrict__ x){
  int bid = blockIdx.x;
  int bh = bid & 31;
  int j = bid >> 5;
  int qt = (j < 8) ? (15 - j) : (j - 8);
  int b = bh >> 4, h_ = bh & 15;
  int t = threadIdx.x;
  int w = t >> 6, lane = t & 63;
  int lr = lane & 15, lg = lane >> 4;

  __shared__ u16 sK [2][64][72];
  __shared__ u16 sVt[2][64][72];
  __shared__ u16 sP [64][72];      // wave-private rows: no cross-wave access

  // Q pre-scaled by 1/sqrt(1024) = 2^-5 (exact in bf16)
  const u16* qbase = qkv + ((size_t)(b*Tn + qt*64 + w*16 + lr)) * 3*Dm + h_*64 + lg*8;
  bf16x8 qf[2];
  #pragma unroll
  for (int i = 0; i < 2; i++){
    u16x8 raw = *(const u16x8*)(qbase + i * 32);
    #pragma unroll
    for (int u = 0; u < 8; u++) qf[i][u] = (__bf16)(bf2f(raw[u]) * 0.03125f);
  }

  f32x4 o_[4] = {};
  float m_[4], l_[4];
  #pragma unroll
  for (int r = 0; r < 4; r++){ m_[r] = -INFINITY; l_[r] = 0.0f; }

  int sr = t >> 2, scc = (t & 3) * 16;
  const u16* kbase = qkv + ((size_t)(b*Tn + sr)) * 3*Dm + Dm + h_*64 + scc;
  const u16* vbase = vT + ((size_t)(bh*64 + sr)) * Tn + scc;
  int4 kr0, kr1, vr0, vr1;

  kr0 = *(const int4*)(kbase);     kr1 = *(const int4*)(kbase + 8);
  vr0 = *(const int4*)(vbase);     vr1 = *(const int4*)(vbase + 8);
  *(int4*)&sK [0][sr][scc]     = kr0;  *(int4*)&sK [0][sr][scc + 8] = kr1;
  *(int4*)&sVt[0][sr][scc]     = vr0;  *(int4*)&sVt[0][sr][scc + 8] = vr1;

  for (int kt = 0; kt <= qt; kt++){
    int cur = kt & 1;
    if (kt < qt){                  // T14: issue next tile's loads before compute
      const u16* kb = kbase + (size_t)(kt + 1) * 64 * 3 * Dm;
      const u16* vb = vbase + (kt + 1) * 64;
      kr0 = *(const int4*)(kb);    kr1 = *(const int4*)(kb + 8);
      vr0 = *(const int4*)(vb);    vr1 = *(const int4*)(vb + 8);
    }
    __syncthreads();

    // S = Q.K^T (Q pre-scaled)
    f32x4 s[4] = {};
    __builtin_amdgcn_s_setprio(1);
    #pragma unroll
    for (int kf = 0; kf < 2; kf++){
      #pragma unroll
      for (int nf = 0; nf < 4; nf++){
        bf16x8 kfrag = *(const bf16x8*)&sK[cur][nf*16 + lr][kf*32 + lg*8];
        s[nf] = __builtin_amdgcn_mfma_f32_16x16x32_bf16(qf[kf], kfrag, s[nf], 0, 0, 0);
      }
    }
    __builtin_amdgcn_s_setprio(0);

    bool lastt = (kt == qt);
    float tmax[4] = {-INFINITY, -INFINITY, -INFINITY, -INFINITY};
    #pragma unroll
    for (int nf = 0; nf < 4; nf++)
      #pragma unroll
      for (int r = 0; r < 4; r++){
        float v = s[nf][r];
        if (lastt){
          int kkg = nf*16 + lr, qg = w*16 + lg*4 + r;
          if (kkg > qg) v = -INFINITY;
        }
        s[nf][r] = v;
        tmax[r] = fmaxf(tmax[r], v);
      }
    #pragma unroll
    for (int r = 0; r < 4; r++){
      tmax[r] = fmaxf(tmax[r], __shfl_xor(tmax[r], 1));
      tmax[r] = fmaxf(tmax[r], __shfl_xor(tmax[r], 2));
      tmax[r] = fmaxf(tmax[r], __shfl_xor(tmax[r], 4));
      tmax[r] = fmaxf(tmax[r], __shfl_xor(tmax[r], 8));
    }
    float resc[4], psum[4];
    #pragma unroll
    for (int r = 0; r < 4; r++){
      float nm = fmaxf(m_[r], tmax[r]);
      resc[r] = __expf(m_[r] - nm);
      m_[r] = nm;
      psum[r] = 0.0f;
    }
    #pragma unroll
    for (int nf = 0; nf < 4; nf++)
      #pragma unroll
      for (int r = 0; r < 4; r++){
        float pv = __expf(s[nf][r] - m_[r]);
        s[nf][r] = pv;
        psum[r] += pv;
      }
    #pragma unroll
    for (int r = 0; r < 4; r++){
      psum[r] += __shfl_xor(psum[r], 1);
      psum[r] += __shfl_xor(psum[r], 2);
      psum[r] += __shfl_xor(psum[r], 4);
      psum[r] += __shfl_xor(psum[r], 8);
      l_[r] = l_[r] * resc[r] + psum[r];
    }
    #pragma unroll
    for (int df = 0; df < 4; df++)
      #pragma unroll
      for (int r = 0; r < 4; r++)
        o_[df][r] *= resc[r];

    // P C-frag -> wave-private LDS rows -> A-frag (no barrier: wave-local)
    #pragma unroll
    for (int nf = 0; nf < 4; nf++)
      #pragma unroll
      for (int r = 0; r < 4; r++)
        sP[w*16 + lg*4 + r][nf*16 + lr] = f2bf(s[nf][r]);

    __builtin_amdgcn_s_setprio(1);
    #pragma unroll
    for (int kf = 0; kf < 2; kf++){
      bf16x8 pfrag = *(const bf16x8*)&sP[w*16 + lr][kf*32 + lg*8];
      #pragma unroll
      for (int df = 0; df < 4; df++){
        bf16x8 vfrag = *(const bf16x8*)&sVt[cur][df*16 + lr][kf*32 + lg*8];
        o_[df] = __builtin_amdgcn_mfma_f32_16x16x32_bf16(pfrag, vfrag, o_[df], 0, 0, 0);
      }
    }
    __builtin_amdgcn_s_setprio(0);

    if (kt < qt){                  // write-late: land next tile in the other buffer
      int nxt = cur ^ 1;
      *(int4*)&sK [nxt][sr][scc]     = kr0;  *(int4*)&sK [nxt][sr][scc + 8] = kr1;
      *(int4*)&sVt[nxt][sr][scc]     = vr0;  *(int4*)&sVt[nxt][sr][scc + 8] = vr1;
    }
  }

  float inv[4];
  #pragma unroll
  for (int r = 0; r < 4; r++) inv[r] = 1.0f / l_[r];
  #pragma unroll
  for (int df = 0; df < 4; df++)
    #pragma unroll
    for (int r = 0; r < 4; r++){
      float* xr = x + ((size_t)(b*Tn + qt*64 + w*16 + lg*4 + r)) * Dm + h_*64 + df*16 + lr;
      *xr += o_[df][r] * inv[r];
    }
}

// ---------------- host orchestration ----------------
extern "C" void kernel_launch(void* const* d_in, const int* in_sizes, int n_in,
                              void* d_out, int out_size, void* d_ws, size_t ws_size,
                              hipStream_t stream){
  const int*   idx   = (const int*)  d_in[0];
  const float* emb   = (const float*)d_in[1];
  const float* pos   = (const float*)d_in[2];
  const float* ln1w  = (const float*)d_in[3];
  const float* ln1b  = (const float*)d_in[4];
  const float* qkvw  = (const float*)d_in[5];
  const float* qkvb  = (const float*)d_in[6];
  const float* ln2w  = (const float*)d_in[7];
  const float* ln2b  = (const float*)d_in[8];
  const float* fc1w  = (const float*)d_in[9];
  const float* fc1b  = (const float*)d_in[10];
  const float* fc2w  = (const float*)d_in[11];
  const float* fc2b  = (const float*)d_in[12];
  const float* lnfw  = (const float*)d_in[13];
  const float* lnfb  = (const float*)d_in[14];
  const float* headw = (const float*)d_in[15];
  const float* headb = (const float*)d_in[16];
  float* out = (float*)d_out;

  char* ws = (char*)d_ws;
  float* x   = (float*)(ws);                       // 8 MB  [2048][1024] f32
  u16*   h   = (u16*)  (ws + (8u  << 20));         // 4 MB  [2048][1024] bf16
  u16*   qkv = (u16*)  (ws + (12u << 20));         // 12 MB [2048][3072] bf16
  u16*   f1  = (u16*)  (ws + (24u << 20));         // 16 MB [2048][4096] bf16
  u16*   Bt  = (u16*)  (ws + (40u << 20));         // 8 MB transposed-weight panel
  u16*   vT  = (u16*)  (ws + (48u << 20));         // 4 MB [32 bh][64 d][1024 t] bf16
  u16*   BtF = (u16*)  (ws + (12u << 20));         // 103 MB full head panel (reuses dead qkv/f1/Bt/vT)

  embed_kernel<<<NTOK, 256, 0, stream>>>(idx, emb, pos, x);

  for (int l = 0; l < Ln; l++){
    // --- attention block ---
    ln_kernel<<<NTOK, 256, 0, stream>>>(x, ln1w + l*Dm, ln1b + l*Dm, h);
    transpose_w<<<dim3(3072/64, Dm/64), 256, 0, stream>>>(qkvw + (size_t)l*Dm*3072, Bt, 3072, Dm, 0);
    gemm_kernel<0><<<dim3(3072/BN, NTOK/BM), 256, 0, stream>>>(h, Bt, qkvb + l*3072, qkv, nullptr, vT, Dm, 3072, 0);
    attn_mfma<<<512, 256, 0, stream>>>(qkv, vT, x);
    // --- MLP block ---
    ln_kernel<<<NTOK, 256, 0, stream>>>(x, ln2w + l*Dm, ln2b + l*Dm, h);
    transpose_w<<<dim3(Fm/64, Dm/64), 256, 0, stream>>>(fc1w + (size_t)l*Dm*Fm, Bt, Fm, Dm, 0);
    gemm_kernel<1><<<dim3(Fm/BN, NTOK/BM), 256, 0, stream>>>(h, Bt, fc1b + l*Fm, f1, nullptr, nullptr, Dm, Fm, 0);
    transpose_w<<<dim3(Dm/64, Fm/64), 256, 0, stream>>>(fc2w + (size_t)l*Fm*Dm, Bt, Dm, Fm, 0);
    gemm_kernel<2><<<dim3(Dm/BN, NTOK/BM), 256, 0, stream>>>(f1, Bt, fc2b + l*Dm, nullptr, x, nullptr, Fm, Dm, 0);
  }

  ln_kernel<<<NTOK, 256, 0, stream>>>(x, lnfw, lnfb, h);

  if (ws_size >= (116u << 20)){
    // single full-vocab transpose + one big GEMM (6288 WGs): no chunk serialization
    transpose_w<<<dim3(786, Dm/64), 256, 0, stream>>>(headw, BtF, Vn, Dm, 0);
    gemm_kernel<3><<<dim3(393, NTOK/BM), 256, 0, stream>>>(h, BtF, headb, out, nullptr, nullptr, Dm, Vn, 0);
  } else {
    const int CHUNK = 4096;
    for (int c0 = 0; c0 < Vn; c0 += CHUNK){
      int W = Vn - c0; if (W > CHUNK) W = CHUNK;
      int ngx = (W + BN - 1) / BN;
      transpose_w<<<dim3(ngx * 2, Dm/64), 256, 0, stream>>>(headw, Bt, Vn, Dm, c0);
      gemm_kernel<3><<<dim3(ngx, NTOK/BM), 256, 0, stream>>>(h, Bt, headb, out, nullptr, nullptr, Dm, Vn, c0);
    }
  }
}

// Round 5
// 1916.315 us; speedup vs baseline: 2.2784x; 1.0436x over previous
//
#include <hip/hip_runtime.h>
#include <math.h>

#define Ln 8
#define Bn 2
#define Tn 1024
#define Dm 1024
#define Hn 16
#define Fm 4096
#define Vn 50257
#define NTOK 2048   // B*T

typedef unsigned short u16;
typedef u16   u16x8  __attribute__((ext_vector_type(8)));
typedef __bf16 bf16x8 __attribute__((ext_vector_type(8)));
typedef float f32x4  __attribute__((ext_vector_type(4)));

__device__ __forceinline__ u16 f2bf(float f){
  unsigned u = __builtin_bit_cast(unsigned, f);
  u += 0x7FFFu + ((u >> 16) & 1u);            // RNE
  return (u16)(u >> 16);
}
__device__ __forceinline__ float bf2f(u16 s){
  return __builtin_bit_cast(float, ((unsigned)s) << 16);
}
__device__ __forceinline__ float gelu_f(float v){
  return 0.5f * v * (1.0f + erff(v * 0.70710678118654752440f));
}
__device__ __forceinline__ void gload16(const void* g, void* l){
  __builtin_amdgcn_global_load_lds(
      (const __attribute__((address_space(1))) void*)g,
      (__attribute__((address_space(3))) void*)l, 16, 0, 0);
}

// ---------------- embedding ----------------
__global__ __launch_bounds__(256) void embed_kernel(const int* __restrict__ idx,
                                                    const float* __restrict__ emb,
                                                    const float* __restrict__ pos,
                                                    float* __restrict__ x){
  int row = blockIdx.x;
  int t = row & (Tn - 1);
  int id = idx[row];
  const float4* e = (const float4*)(emb + (size_t)id * Dm);
  const float4* p = (const float4*)(pos + (size_t)t * Dm);
  float4* o = (float4*)(x + (size_t)row * Dm);
  int i = threadIdx.x;
  float4 a = e[i], b = p[i];
  o[i] = make_float4(a.x + b.x, a.y + b.y, a.z + b.z, a.w + b.w);
}

// ---------------- layernorm (f32 in, bf16 out) ----------------
__global__ __launch_bounds__(256) void ln_kernel(const float* __restrict__ xin,
                                                 const float* __restrict__ w,
                                                 const float* __restrict__ bb,
                                                 u16* __restrict__ out){
  int row = blockIdx.x;
  int t = threadIdx.x;
  float4 v = ((const float4*)(xin + (size_t)row * Dm))[t];
  float s  = v.x + v.y + v.z + v.w;
  float s2 = v.x*v.x + v.y*v.y + v.z*v.z + v.w*v.w;
  #pragma unroll
  for (int off = 1; off < 64; off <<= 1){
    s  += __shfl_xor(s, off);
    s2 += __shfl_xor(s2, off);
  }
  __shared__ float red[8];
  int wv = t >> 6, lane = t & 63;
  if (lane == 0){ red[wv] = s; red[4 + wv] = s2; }
  __syncthreads();
  s  = red[0] + red[1] + red[2] + red[3];
  s2 = red[4] + red[5] + red[6] + red[7];
  float mean = s * (1.0f / Dm);
  float var  = s2 * (1.0f / Dm) - mean * mean;
  float rs = rsqrtf(var + 1e-5f);
  float4 wv4 = ((const float4*)w)[t];
  float4 bv4 = ((const float4*)bb)[t];
  u16 o4[4];
  o4[0] = f2bf((v.x - mean) * rs * wv4.x + bv4.x);
  o4[1] = f2bf((v.y - mean) * rs * wv4.y + bv4.y);
  o4[2] = f2bf((v.z - mean) * rs * wv4.z + bv4.z);
  o4[3] = f2bf((v.w - mean) * rs * wv4.w + bv4.w);
  *(uint2*)(out + (size_t)row * Dm + t * 4) = *(uint2*)o4;
}

// ---------------- transpose tile: f32 src[k][srcCol+*] -> bf16 dst[dstRow+*][k] ----------------
__device__ __forceinline__ void trans_tile(const float* __restrict__ src,
                                           u16* __restrict__ dst,
                                           int N, int K, int srcCol, int dstRow, int k0){
  __shared__ float tile[64][66];
  int t = threadIdx.x;
  int rr = t >> 4, nc = (t & 15) * 4;
  #pragma unroll
  for (int u = 0; u < 4; u++){
    int kk = rr + u * 16;
    int gn = srcCol + nc;
    const float* sp = src + (size_t)(k0 + kk) * N;
    float4 v;
    if (gn + 3 < N) v = *(const float4*)(sp + gn);
    else {
      v.x = (gn     < N) ? sp[gn]     : 0.0f;
      v.y = (gn + 1 < N) ? sp[gn + 1] : 0.0f;
      v.z = (gn + 2 < N) ? sp[gn + 2] : 0.0f;
      v.w = (gn + 3 < N) ? sp[gn + 3] : 0.0f;
    }
    tile[kk][nc]     = v.x;
    tile[kk][nc + 1] = v.y;
    tile[kk][nc + 2] = v.z;
    tile[kk][nc + 3] = v.w;
  }
  __syncthreads();
  int np = t >> 2, c = t & 3;
  u16* dp = dst + (size_t)(dstRow + np) * K + k0;
  u16 pk[8];
  #pragma unroll
  for (int j = 0; j < 8; j++) pk[j] = f2bf(tile[c*8 + j][np]);
  *(int4*)(dp + c*8) = *(int4*)pk;
  #pragma unroll
  for (int j = 0; j < 8; j++) pk[j] = f2bf(tile[32 + c*8 + j][np]);
  *(int4*)(dp + 32 + c*8) = *(int4*)pk;
}

__global__ __launch_bounds__(256) void transpose_w(const float* __restrict__ Bw,
                                                   u16* __restrict__ Bt,
                                                   int N, int K, int c0){
  int n0 = blockIdx.x * 64, k0 = blockIdx.y * 64;
  trans_tile(Bw, Bt, N, K, c0 + n0, n0, k0);
}

// all layer weights + head in ONE dispatch.
// ranges: qkv 8x768=6144 | fc1 8x1024=8192 | fc2 8x1024=8192 | head 786x16=12576
__global__ __launch_bounds__(256) void mega_transpose(const float* __restrict__ qkvw,
                                                      const float* __restrict__ fc1w,
                                                      const float* __restrict__ fc2w,
                                                      const float* __restrict__ headw,
                                                      u16* __restrict__ Wq,
                                                      u16* __restrict__ W1,
                                                      u16* __restrict__ W2,
                                                      u16* __restrict__ Wh){
  int id = blockIdx.x;
  const float* src; u16* dst; int N, K, n0, k0;
  if (id < 6144){
    int l = id / 768, r = id % 768;
    n0 = (r % 48) * 64; k0 = (r / 48) * 64;
    src = qkvw + (size_t)l * Dm * 3072; dst = Wq + (size_t)l * 3072 * Dm;
    N = 3072; K = Dm;
  } else if (id < 14336){
    int id2 = id - 6144;
    int l = id2 / 1024, r = id2 % 1024;
    n0 = (r % 64) * 64; k0 = (r / 64) * 64;
    src = fc1w + (size_t)l * Dm * Fm; dst = W1 + (size_t)l * Fm * Dm;
    N = Fm; K = Dm;
  } else if (id < 22528){
    int id2 = id - 14336;
    int l = id2 / 1024, r = id2 % 1024;
    n0 = (r % 16) * 64; k0 = (r / 16) * 64;
    src = fc2w + (size_t)l * Fm * Dm; dst = W2 + (size_t)l * Dm * Fm;
    N = Dm; K = Fm;
  } else {
    int id2 = id - 22528;
    n0 = (id2 % 786) * 64; k0 = (id2 / 786) * 64;
    src = headw; dst = Wh;
    N = Vn; K = Dm;                 // zero-fills cols 50257..50303
  }
  trans_tile(src, dst, N, K, n0, n0, k0);
}

// ---------------- GEMM: C[2048][Nout] = A(bf16 [2048][K]) @ Bt(bf16 [N][K])^T ----------------
// generic tile: BMt x BNt, wave grid WM x WN (4 waves), frag repeats MR x NR.
// SWZ: 1D grid, XCD-chunked m-fastest decode (assumes 16 m-tiles, gridDim.x % 8 == 0).
// MODE 0: out bf16 = v+bias (qkv); V cols (>=2048) routed transposed into vT
// MODE 1: out bf16 = gelu(v+bias)      (fc1)
// MODE 2: resid += gelu(v+bias)        (fc2)
// MODE 3: out f32 = v+bias, col guard  (head)
template<int MODE, int BMt, int BNt, int WM, int WN, bool SWZ>
__global__ __launch_bounds__(256) void gemm_kernel(const u16* __restrict__ A,
                                                   const u16* __restrict__ Bt,
                                                   const float* __restrict__ bias,
                                                   void* __restrict__ outp,
                                                   float* __restrict__ resid,
                                                   u16* __restrict__ vT,
                                                   int K, int Nout, int c0){
  constexpr int MR = BMt / (WM * 16);
  constexpr int NR = BNt / (WN * 16);
  __shared__ u16 sA[BMt][64];
  __shared__ u16 sB[BNt][64];
  int t = threadIdx.x;
  int lane = t & 63, w = t >> 6;
  int wm = w / WN, wn = w % WN;
  int lr = lane & 15, lg = lane >> 4;
  int m0, n0;
  if (SWZ){
    int orig = blockIdx.x;
    int q = gridDim.x >> 3;                         // gridDim.x % 8 == 0
    int wg = (orig & 7) * q + (orig >> 3);          // XCD-chunked (bijective)
    m0 = (wg & 15) * BMt;                           // m-fastest: B-tile reuse in-XCD
    n0 = (wg >> 4) * BNt;
  } else {
    m0 = blockIdx.y * BMt; n0 = blockIdx.x * BNt;
  }

  f32x4 acc[MR][NR] = {};

  int srow = lane >> 3, scol = (lane & 7) * 8;
  int cswz = ((lr >> 2) & 3) << 4;

  for (int k0 = 0; k0 < K; k0 += 64){
    __syncthreads();
    #pragma unroll
    for (int i = 0; i < BMt/32; i++){
      int rbase = i*32 + w*8;
      int r = rbase + srow;
      int gc = scol ^ (((r >> 2) & 3) << 4);        // pre-swizzled global source (m173)
      gload16(A + (size_t)(m0 + r) * K + k0 + gc, (char*)&sA[rbase][0]);
    }
    #pragma unroll
    for (int i = 0; i < BNt/32; i++){
      int rbase = i*32 + w*8;
      int r = rbase + srow;
      int gc = scol ^ (((r >> 2) & 3) << 4);
      gload16(Bt + (size_t)(n0 + r) * K + k0 + gc, (char*)&sB[rbase][0]);
    }
    __syncthreads();
    #pragma unroll
    for (int kk = 0; kk < 2; kk++){
      bf16x8 af[MR], bfr[NR];
      #pragma unroll
      for (int i = 0; i < MR; i++) af[i]  = *(const bf16x8*)&sA[wm*(MR*16) + i*16 + lr][(kk*32 + lg*8) ^ cswz];
      #pragma unroll
      for (int j = 0; j < NR; j++) bfr[j] = *(const bf16x8*)&sB[wn*(NR*16) + j*16 + lr][(kk*32 + lg*8) ^ cswz];
      #pragma unroll
      for (int i = 0; i < MR; i++)
        #pragma unroll
        for (int j = 0; j < NR; j++)
          acc[i][j] = __builtin_amdgcn_mfma_f32_16x16x32_bf16(af[i], bfr[j], acc[i][j], 0, 0, 0);
    }
  }

  #pragma unroll
  for (int i = 0; i < MR; i++){
    int gr0 = m0 + wm*(MR*16) + i*16 + lg*4;
    #pragma unroll
    for (int j = 0; j < NR; j++){
      int gc = c0 + n0 + wn*(NR*16) + j*16 + lr;
      if (MODE == 3 && gc >= Nout) continue;
      float bb = bias[gc];
      if (MODE == 0 && gc >= 2048){
        int hh = (gc - 2048) >> 6, dd = (gc - 2048) & 63;
        int b_ = gr0 >> 10, tt = gr0 & 1023;
        u16 pk[4];
        #pragma unroll
        for (int r = 0; r < 4; r++) pk[r] = f2bf(acc[i][j][r] + bb);
        *(uint2*)&vT[((size_t)((b_*Hn + hh)*64 + dd))*Tn + tt] = *(uint2*)pk;
        continue;
      }
      #pragma unroll
      for (int r = 0; r < 4; r++){
        float v = acc[i][j][r] + bb;
        size_t oi = (size_t)(gr0 + r) * Nout + gc;
        if (MODE == 0)      ((u16*)outp)[oi] = f2bf(v);
        else if (MODE == 1) ((u16*)outp)[oi] = f2bf(gelu_f(v));
        else if (MODE == 2) resid[oi] = resid[oi] + gelu_f(v);
        else                ((float*)outp)[oi] = v;
      }
    }
  }
}

// ---------------- MFMA fused causal attention (double-buffered K/V, T14 staging) ----------------
// 1D grid 512; bh = bid&31; j = bid>>5; qt = j<8 ? 15-j : j-8  (heavy-first, paired load balance)
__global__ __launch_bounds__(256) void attn_mfma(const u16* __restrict__ qkv,
                                                 const u16* __restrict__ vT,
                                                 float* __restrict__ x){
  int bid = blockIdx.x;
  int bh = bid & 31;
  int j = bid >> 5;
  int qt = (j < 8) ? (15 - j) : (j - 8);
  int b = bh >> 4, h_ = bh & 15;
  int t = threadIdx.x;
  int w = t >> 6, lane = t & 63;
  int lr = lane & 15, lg = lane >> 4;

  __shared__ u16 sK [2][64][72];
  __shared__ u16 sVt[2][64][72];
  __shared__ u16 sP [64][72];      // wave-private rows: no cross-wave access

  // Q pre-scaled by 1/sqrt(1024) = 2^-5 (exact in bf16)
  const u16* qbase = qkv + ((size_t)(b*Tn + qt*64 + w*16 + lr)) * 3*Dm + h_*64 + lg*8;
  bf16x8 qf[2];
  #pragma unroll
  for (int i = 0; i < 2; i++){
    u16x8 raw = *(const u16x8*)(qbase + i * 32);
    #pragma unroll
    for (int u = 0; u < 8; u++) qf[i][u] = (__bf16)(bf2f(raw[u]) * 0.03125f);
  }

  f32x4 o_[4] = {};
  float m_[4], l_[4];
  #pragma unroll
  for (int r = 0; r < 4; r++){ m_[r] = -INFINITY; l_[r] = 0.0f; }

  int sr = t >> 2, scc = (t & 3) * 16;
  const u16* kbase = qkv + ((size_t)(b*Tn + sr)) * 3*Dm + Dm + h_*64 + scc;
  const u16* vbase = vT + ((size_t)(bh*64 + sr)) * Tn + scc;
  int4 kr0, kr1, vr0, vr1;

  kr0 = *(const int4*)(kbase);     kr1 = *(const int4*)(kbase + 8);
  vr0 = *(const int4*)(vbase);     vr1 = *(const int4*)(vbase + 8);
  *(int4*)&sK [0][sr][scc]     = kr0;  *(int4*)&sK [0][sr][scc + 8] = kr1;
  *(int4*)&sVt[0][sr][scc]     = vr0;  *(int4*)&sVt[0][sr][scc + 8] = vr1;

  for (int kt = 0; kt <= qt; kt++){
    int cur = kt & 1;
    if (kt < qt){                  // T14: issue next tile's loads before compute
      const u16* kb = kbase + (size_t)(kt + 1) * 64 * 3 * Dm;
      const u16* vb = vbase + (kt + 1) * 64;
      kr0 = *(const int4*)(kb);    kr1 = *(const int4*)(kb + 8);
      vr0 = *(const int4*)(vb);    vr1 = *(const int4*)(vb + 8);
    }
    __syncthreads();

    // S = Q.K^T (Q pre-scaled)
    f32x4 s[4] = {};
    __builtin_amdgcn_s_setprio(1);
    #pragma unroll
    for (int kf = 0; kf < 2; kf++){
      #pragma unroll
      for (int nf = 0; nf < 4; nf++){
        bf16x8 kfrag = *(const bf16x8*)&sK[cur][nf*16 + lr][kf*32 + lg*8];
        s[nf] = __builtin_amdgcn_mfma_f32_16x16x32_bf16(qf[kf], kfrag, s[nf], 0, 0, 0);
      }
    }
    __builtin_amdgcn_s_setprio(0);

    bool lastt = (kt == qt);
    float tmax[4] = {-INFINITY, -INFINITY, -INFINITY, -INFINITY};
    #pragma unroll
    for (int nf = 0; nf < 4; nf++)
      #pragma unroll
      for (int r = 0; r < 4; r++){
        float v = s[nf][r];
        if (lastt){
          int kkg = nf*16 + lr, qg = w*16 + lg*4 + r;
          if (kkg > qg) v = -INFINITY;
        }
        s[nf][r] = v;
        tmax[r] = fmaxf(tmax[r], v);
      }
    #pragma unroll
    for (int r = 0; r < 4; r++){
      tmax[r] = fmaxf(tmax[r], __shfl_xor(tmax[r], 1));
      tmax[r] = fmaxf(tmax[r], __shfl_xor(tmax[r], 2));
      tmax[r] = fmaxf(tmax[r], __shfl_xor(tmax[r], 4));
      tmax[r] = fmaxf(tmax[r], __shfl_xor(tmax[r], 8));
    }
    float resc[4], psum[4];
    #pragma unroll
    for (int r = 0; r < 4; r++){
      float nm = fmaxf(m_[r], tmax[r]);
      resc[r] = __expf(m_[r] - nm);
      m_[r] = nm;
      psum[r] = 0.0f;
    }
    #pragma unroll
    for (int nf = 0; nf < 4; nf++)
      #pragma unroll
      for (int r = 0; r < 4; r++){
        float pv = __expf(s[nf][r] - m_[r]);
        s[nf][r] = pv;
        psum[r] += pv;
      }
    #pragma unroll
    for (int r = 0; r < 4; r++){
      psum[r] += __shfl_xor(psum[r], 1);
      psum[r] += __shfl_xor(psum[r], 2);
      psum[r] += __shfl_xor(psum[r], 4);
      psum[r] += __shfl_xor(psum[r], 8);
      l_[r] = l_[r] * resc[r] + psum[r];
    }
    #pragma unroll
    for (int df = 0; df < 4; df++)
      #pragma unroll
      for (int r = 0; r < 4; r++)
        o_[df][r] *= resc[r];

    // P C-frag -> wave-private LDS rows -> A-frag (no barrier: wave-local)
    #pragma unroll
    for (int nf = 0; nf < 4; nf++)
      #pragma unroll
      for (int r = 0; r < 4; r++)
        sP[w*16 + lg*4 + r][nf*16 + lr] = f2bf(s[nf][r]);

    __builtin_amdgcn_s_setprio(1);
    #pragma unroll
    for (int kf = 0; kf < 2; kf++){
      bf16x8 pfrag = *(const bf16x8*)&sP[w*16 + lr][kf*32 + lg*8];
      #pragma unroll
      for (int df = 0; df < 4; df++){
        bf16x8 vfrag = *(const bf16x8*)&sVt[cur][df*16 + lr][kf*32 + lg*8];
        o_[df] = __builtin_amdgcn_mfma_f32_16x16x32_bf16(pfrag, vfrag, o_[df], 0, 0, 0);
      }
    }
    __builtin_amdgcn_s_setprio(0);

    if (kt < qt){                  // write-late: land next tile in the other buffer
      int nxt = cur ^ 1;
      *(int4*)&sK [nxt][sr][scc]     = kr0;  *(int4*)&sK [nxt][sr][scc + 8] = kr1;
      *(int4*)&sVt[nxt][sr][scc]     = vr0;  *(int4*)&sVt[nxt][sr][scc + 8] = vr1;
    }
  }

  float inv[4];
  #pragma unroll
  for (int r = 0; r < 4; r++) inv[r] = 1.0f / l_[r];
  #pragma unroll
  for (int df = 0; df < 4; df++)
    #pragma unroll
    for (int r = 0; r < 4; r++){
      float* xr = x + ((size_t)(b*Tn + qt*64 + w*16 + lg*4 + r)) * Dm + h_*64 + df*16 + lr;
      *xr += o_[df][r] * inv[r];
    }
}

// ---------------- host orchestration ----------------
extern "C" void kernel_launch(void* const* d_in, const int* in_sizes, int n_in,
                              void* d_out, int out_size, void* d_ws, size_t ws_size,
                              hipStream_t stream){
  const int*   idx   = (const int*)  d_in[0];
  const float* emb   = (const float*)d_in[1];
  const float* pos   = (const float*)d_in[2];
  const float* ln1w  = (const float*)d_in[3];
  const float* ln1b  = (const float*)d_in[4];
  const float* qkvw  = (const float*)d_in[5];
  const float* qkvb  = (const float*)d_in[6];
  const float* ln2w  = (const float*)d_in[7];
  const float* ln2b  = (const float*)d_in[8];
  const float* fc1w  = (const float*)d_in[9];
  const float* fc1b  = (const float*)d_in[10];
  const float* fc2w  = (const float*)d_in[11];
  const float* fc2b  = (const float*)d_in[12];
  const float* lnfw  = (const float*)d_in[13];
  const float* lnfb  = (const float*)d_in[14];
  const float* headw = (const float*)d_in[15];
  const float* headb = (const float*)d_in[16];
  float* out = (float*)d_out;

  const size_t MB = 1u << 20;
  char* ws = (char*)d_ws;
  float* x   = (float*)(ws);                       // 8 MB  [2048][1024] f32
  u16*   h   = (u16*)  (ws + 8*MB);                // 4 MB  [2048][1024] bf16
  u16*   qkv = (u16*)  (ws + 12*MB);               // 12 MB [2048][3072] bf16
  u16*   f1  = (u16*)  (ws + 24*MB);               // 16 MB [2048][4096] bf16

  bool mega    = ws_size >= 320*MB;
  bool bighead = ws_size >= 116*MB;

  u16 *vT, *Bt = nullptr, *BtF = nullptr, *Wq = nullptr, *W1 = nullptr, *W2 = nullptr, *Wh = nullptr;
  if (mega){
    vT = (u16*)(ws + 40*MB);                       // 4 MB
    Wq = (u16*)(ws + 44*MB);                       // 48 MB  (8 x 3072x1024)
    W1 = (u16*)(ws + 92*MB);                       // 64 MB  (8 x 4096x1024)
    W2 = (u16*)(ws + 156*MB);                      // 64 MB  (8 x 1024x4096)
    Wh = (u16*)(ws + 220*MB);                      // 98.3 MB (50304x1024)
  } else {
    Bt  = (u16*)(ws + 40*MB);                      // 8 MB per-layer panel
    vT  = (u16*)(ws + 48*MB);                      // 4 MB
    BtF = (u16*)(ws + 12*MB);                      // 103 MB head panel (reuses dead qkv/f1/Bt/vT)
  }

  if (mega)
    mega_transpose<<<35104, 256, 0, stream>>>(qkvw, fc1w, fc2w, headw, Wq, W1, W2, Wh);

  embed_kernel<<<NTOK, 256, 0, stream>>>(idx, emb, pos, x);

  for (int l = 0; l < Ln; l++){
    const u16* Bq = mega ? Wq + (size_t)l*3072*Dm : Bt;
    const u16* B1 = mega ? W1 + (size_t)l*Fm*Dm   : Bt;
    const u16* B2 = mega ? W2 + (size_t)l*Dm*Fm   : Bt;
    // --- attention block ---
    ln_kernel<<<NTOK, 256, 0, stream>>>(x, ln1w + l*Dm, ln1b + l*Dm, h);
    if (!mega) transpose_w<<<dim3(3072/64, Dm/64), 256, 0, stream>>>(qkvw + (size_t)l*Dm*3072, Bt, 3072, Dm, 0);
    gemm_kernel<0, 64,128,1,4,false><<<dim3(3072/128, NTOK/64), 256, 0, stream>>>(h, Bq, qkvb + l*3072, qkv, nullptr, vT, Dm, 3072, 0);
    attn_mfma<<<512, 256, 0, stream>>>(qkv, vT, x);
    // --- MLP block ---
    ln_kernel<<<NTOK, 256, 0, stream>>>(x, ln2w + l*Dm, ln2b + l*Dm, h);
    if (!mega) transpose_w<<<dim3(Fm/64, Dm/64), 256, 0, stream>>>(fc1w + (size_t)l*Dm*Fm, Bt, Fm, Dm, 0);
    gemm_kernel<1,128,128,2,2,false><<<dim3(Fm/128, NTOK/128), 256, 0, stream>>>(h, B1, fc1b + l*Fm, f1, nullptr, nullptr, Dm, Fm, 0);
    if (!mega) transpose_w<<<dim3(Dm/64, Fm/64), 256, 0, stream>>>(fc2w + (size_t)l*Fm*Dm, Bt, Dm, Fm, 0);
    gemm_kernel<2, 64,128,1,4,false><<<dim3(Dm/128, NTOK/64), 256, 0, stream>>>(f1, B2, fc2b + l*Dm, nullptr, x, nullptr, Fm, Dm, 0);
  }

  ln_kernel<<<NTOK, 256, 0, stream>>>(x, lnfw, lnfb, h);

  if (mega){
    gemm_kernel<3,128,128,2,2,true><<<6288, 256, 0, stream>>>(h, Wh, headb, out, nullptr, nullptr, Dm, Vn, 0);
  } else if (bighead){
    transpose_w<<<dim3(786, Dm/64), 256, 0, stream>>>(headw, BtF, Vn, Dm, 0);
    gemm_kernel<3,128,128,2,2,true><<<6288, 256, 0, stream>>>(h, BtF, headb, out, nullptr, nullptr, Dm, Vn, 0);
  } else {
    const int CHUNK = 4096;
    for (int c0 = 0; c0 < Vn; c0 += CHUNK){
      int W = Vn - c0; if (W > CHUNK) W = CHUNK;
      int ngx = (W + 127) / 128;
      transpose_w<<<dim3(ngx * 2, Dm/64), 256, 0, stream>>>(headw, Bt, Vn, Dm, c0);
      gemm_kernel<3,128,128,2,2,false><<<dim3(ngx, NTOK/128), 256, 0, stream>>>(h, Bt, headb, out, nullptr, nullptr, Dm, Vn, c0);
    }
  }
}

// Round 6
// 1885.012 us; speedup vs baseline: 2.3163x; 1.0166x over previous
//
#include <hip/hip_runtime.h>
#include <math.h>

#define Ln 8
#define Bn 2
#define Tn 1024
#define Dm 1024
#define Hn 16
#define Fm 4096
#define Vn 50257
#define NTOK 2048   // B*T

typedef unsigned short u16;
typedef u16   u16x8  __attribute__((ext_vector_type(8)));
typedef __bf16 bf16x8 __attribute__((ext_vector_type(8)));
typedef float f32x4  __attribute__((ext_vector_type(4)));

__device__ __forceinline__ u16 f2bf(float f){
  unsigned u = __builtin_bit_cast(unsigned, f);
  u += 0x7FFFu + ((u >> 16) & 1u);            // RNE
  return (u16)(u >> 16);
}
__device__ __forceinline__ float bf2f(u16 s){
  return __builtin_bit_cast(float, ((unsigned)s) << 16);
}
__device__ __forceinline__ float gelu_f(float v){
  return 0.5f * v * (1.0f + erff(v * 0.70710678118654752440f));
}
__device__ __forceinline__ void gload16(const void* g, void* l){
  __builtin_amdgcn_global_load_lds(
      (const __attribute__((address_space(1))) void*)g,
      (__attribute__((address_space(3))) void*)l, 16, 0, 0);
}

// ---------------- embedding ----------------
__global__ __launch_bounds__(256) void embed_kernel(const int* __restrict__ idx,
                                                    const float* __restrict__ emb,
                                                    const float* __restrict__ pos,
                                                    float* __restrict__ x){
  int row = blockIdx.x;
  int t = row & (Tn - 1);
  int id = idx[row];
  const float4* e = (const float4*)(emb + (size_t)id * Dm);
  const float4* p = (const float4*)(pos + (size_t)t * Dm);
  float4* o = (float4*)(x + (size_t)row * Dm);
  int i = threadIdx.x;
  float4 a = e[i], b = p[i];
  o[i] = make_float4(a.x + b.x, a.y + b.y, a.z + b.z, a.w + b.w);
}

// ---------------- layernorm (f32 in, bf16 out) ----------------
__global__ __launch_bounds__(256) void ln_kernel(const float* __restrict__ xin,
                                                 const float* __restrict__ w,
                                                 const float* __restrict__ bb,
                                                 u16* __restrict__ out){
  int row = blockIdx.x;
  int t = threadIdx.x;
  float4 v = ((const float4*)(xin + (size_t)row * Dm))[t];
  float s  = v.x + v.y + v.z + v.w;
  float s2 = v.x*v.x + v.y*v.y + v.z*v.z + v.w*v.w;
  #pragma unroll
  for (int off = 1; off < 64; off <<= 1){
    s  += __shfl_xor(s, off);
    s2 += __shfl_xor(s2, off);
  }
  __shared__ float red[8];
  int wv = t >> 6, lane = t & 63;
  if (lane == 0){ red[wv] = s; red[4 + wv] = s2; }
  __syncthreads();
  s  = red[0] + red[1] + red[2] + red[3];
  s2 = red[4] + red[5] + red[6] + red[7];
  float mean = s * (1.0f / Dm);
  float var  = s2 * (1.0f / Dm) - mean * mean;
  float rs = rsqrtf(var + 1e-5f);
  float4 wv4 = ((const float4*)w)[t];
  float4 bv4 = ((const float4*)bb)[t];
  u16 o4[4];
  o4[0] = f2bf((v.x - mean) * rs * wv4.x + bv4.x);
  o4[1] = f2bf((v.y - mean) * rs * wv4.y + bv4.y);
  o4[2] = f2bf((v.z - mean) * rs * wv4.z + bv4.z);
  o4[3] = f2bf((v.w - mean) * rs * wv4.w + bv4.w);
  *(uint2*)(out + (size_t)row * Dm + t * 4) = *(uint2*)o4;
}

// ---------------- transpose tile: f32 src[k][srcCol+*] -> bf16 dst[dstRow+*][k] ----------------
__device__ __forceinline__ void trans_tile(const float* __restrict__ src,
                                           u16* __restrict__ dst,
                                           int N, int K, int srcCol, int dstRow, int k0){
  __shared__ float tile[64][66];
  int t = threadIdx.x;
  int rr = t >> 4, nc = (t & 15) * 4;
  #pragma unroll
  for (int u = 0; u < 4; u++){
    int kk = rr + u * 16;
    int gn = srcCol + nc;
    const float* sp = src + (size_t)(k0 + kk) * N;
    float4 v;
    if (gn + 3 < N) v = *(const float4*)(sp + gn);
    else {
      v.x = (gn     < N) ? sp[gn]     : 0.0f;
      v.y = (gn + 1 < N) ? sp[gn + 1] : 0.0f;
      v.z = (gn + 2 < N) ? sp[gn + 2] : 0.0f;
      v.w = (gn + 3 < N) ? sp[gn + 3] : 0.0f;
    }
    tile[kk][nc]     = v.x;
    tile[kk][nc + 1] = v.y;
    tile[kk][nc + 2] = v.z;
    tile[kk][nc + 3] = v.w;
  }
  __syncthreads();
  int np = t >> 2, c = t & 3;
  u16* dp = dst + (size_t)(dstRow + np) * K + k0;
  u16 pk[8];
  #pragma unroll
  for (int j = 0; j < 8; j++) pk[j] = f2bf(tile[c*8 + j][np]);
  *(int4*)(dp + c*8) = *(int4*)pk;
  #pragma unroll
  for (int j = 0; j < 8; j++) pk[j] = f2bf(tile[32 + c*8 + j][np]);
  *(int4*)(dp + 32 + c*8) = *(int4*)pk;
}

__global__ __launch_bounds__(256) void transpose_w(const float* __restrict__ Bw,
                                                   u16* __restrict__ Bt,
                                                   int N, int K, int c0){
  int n0 = blockIdx.x * 64, k0 = blockIdx.y * 64;
  trans_tile(Bw, Bt, N, K, c0 + n0, n0, k0);
}

// all layer weights + head in ONE dispatch.
// ranges: qkv 8x768=6144 | fc1 8x1024=8192 | fc2 8x1024=8192 | head 788x16=12608
__global__ __launch_bounds__(256) void mega_transpose(const float* __restrict__ qkvw,
                                                      const float* __restrict__ fc1w,
                                                      const float* __restrict__ fc2w,
                                                      const float* __restrict__ headw,
                                                      u16* __restrict__ Wq,
                                                      u16* __restrict__ W1,
                                                      u16* __restrict__ W2,
                                                      u16* __restrict__ Wh){
  int id = blockIdx.x;
  const float* src; u16* dst; int N, K, n0, k0;
  if (id < 6144){
    int l = id / 768, r = id % 768;
    n0 = (r % 48) * 64; k0 = (r / 48) * 64;
    src = qkvw + (size_t)l * Dm * 3072; dst = Wq + (size_t)l * 3072 * Dm;
    N = 3072; K = Dm;
  } else if (id < 14336){
    int id2 = id - 6144;
    int l = id2 / 1024, r = id2 % 1024;
    n0 = (r % 64) * 64; k0 = (r / 64) * 64;
    src = fc1w + (size_t)l * Dm * Fm; dst = W1 + (size_t)l * Fm * Dm;
    N = Fm; K = Dm;
  } else if (id < 22528){
    int id2 = id - 14336;
    int l = id2 / 1024, r = id2 % 1024;
    n0 = (r % 16) * 64; k0 = (r / 16) * 64;
    src = fc2w + (size_t)l * Fm * Dm; dst = W2 + (size_t)l * Dm * Fm;
    N = Dm; K = Fm;
  } else {
    int id2 = id - 22528;
    n0 = (id2 % 788) * 64; k0 = (id2 / 788) * 64;   // 50432 rows, zero-filled past 50257
    src = headw; dst = Wh;
    N = Vn; K = Dm;
  }
  trans_tile(src, dst, N, K, n0, n0, k0);
}

// ---------------- generic 2-phase GEMM (layer GEMMs + fallback) ----------------
// LDS swizzle: physical[r][slot] = logical[r][slot ^ (r&7)] (slot = 8 u16 = 16B)
template<int MODE, int BMt, int BNt, int WM, int WN, bool SWZ>
__global__ __launch_bounds__(256) void gemm_kernel(const u16* __restrict__ A,
                                                   const u16* __restrict__ Bt,
                                                   const float* __restrict__ bias,
                                                   void* __restrict__ outp,
                                                   float* __restrict__ resid,
                                                   u16* __restrict__ vT,
                                                   int K, int Nout, int c0){
  constexpr int MR = BMt / (WM * 16);
  constexpr int NR = BNt / (WN * 16);
  __shared__ u16 sA[BMt][64];
  __shared__ u16 sB[BNt][64];
  int t = threadIdx.x;
  int lane = t & 63, w = t >> 6;
  int wm = w / WN, wn = w % WN;
  int lr = lane & 15, lg = lane >> 4;
  int m0, n0;
  if (SWZ){
    int orig = blockIdx.x;
    int q = gridDim.x >> 3;
    int wg = (orig & 7) * q + (orig >> 3);
    m0 = (wg & 15) * BMt;
    n0 = (wg >> 4) * BNt;
  } else {
    m0 = blockIdx.y * BMt; n0 = blockIdx.x * BNt;
  }

  f32x4 acc[MR][NR] = {};

  int srow = lane >> 3;
  int gcs = ((lane & 7) ^ (lane >> 3)) * 8;        // pre-swizzled global k-col (u16)
  int cswz = (lr & 7) << 3;                        // read-side swizzle

  for (int k0 = 0; k0 < K; k0 += 64){
    __syncthreads();
    #pragma unroll
    for (int i = 0; i < BMt/32; i++){
      int rbase = i*32 + w*8;
      gload16(A + (size_t)(m0 + rbase + srow) * K + k0 + gcs, (char*)&sA[rbase][0]);
    }
    #pragma unroll
    for (int i = 0; i < BNt/32; i++){
      int rbase = i*32 + w*8;
      gload16(Bt + (size_t)(n0 + rbase + srow) * K + k0 + gcs, (char*)&sB[rbase][0]);
    }
    __syncthreads();
    #pragma unroll
    for (int kk = 0; kk < 2; kk++){
      bf16x8 af[MR], bfr[NR];
      #pragma unroll
      for (int i = 0; i < MR; i++) af[i]  = *(const bf16x8*)&sA[wm*(MR*16) + i*16 + lr][(kk*32 + lg*8) ^ cswz];
      #pragma unroll
      for (int j = 0; j < NR; j++) bfr[j] = *(const bf16x8*)&sB[wn*(NR*16) + j*16 + lr][(kk*32 + lg*8) ^ cswz];
      #pragma unroll
      for (int i = 0; i < MR; i++)
        #pragma unroll
        for (int j = 0; j < NR; j++)
          acc[i][j] = __builtin_amdgcn_mfma_f32_16x16x32_bf16(af[i], bfr[j], acc[i][j], 0, 0, 0);
    }
  }

  #pragma unroll
  for (int i = 0; i < MR; i++){
    int gr0 = m0 + wm*(MR*16) + i*16 + lg*4;
    #pragma unroll
    for (int j = 0; j < NR; j++){
      int gc = c0 + n0 + wn*(NR*16) + j*16 + lr;
      if (MODE == 3 && gc >= Nout) continue;
      float bb = bias[gc];
      if (MODE == 0 && gc >= 2048){
        int hh = (gc - 2048) >> 6, dd = (gc - 2048) & 63;
        int b_ = gr0 >> 10, tt = gr0 & 1023;
        u16 pk[4];
        #pragma unroll
        for (int r = 0; r < 4; r++) pk[r] = f2bf(acc[i][j][r] + bb);
        *(uint2*)&vT[((size_t)((b_*Hn + hh)*64 + dd))*Tn + tt] = *(uint2*)pk;
        continue;
      }
      #pragma unroll
      for (int r = 0; r < 4; r++){
        float v = acc[i][j][r] + bb;
        size_t oi = (size_t)(gr0 + r) * Nout + gc;
        if (MODE == 0)      ((u16*)outp)[oi] = f2bf(v);
        else if (MODE == 1) ((u16*)outp)[oi] = f2bf(gelu_f(v));
        else if (MODE == 2) resid[oi] = resid[oi] + gelu_f(v);
        else                ((float*)outp)[oi] = v;
      }
    }
  }
}

// ---------------- 8-phase 256x256 head GEMM (T1+T2+T3+T4+T5) ----------------
// C[2048][50257] = A[2048][1024] @ Wh[50432][1024]^T + bias; f32 out.
// 512 thr = 8 waves (2M x 4N); wave owns 128x64; acc[8][4]; BK=64, NT=16, 8 iters.
// LDS 128 KiB: sA/sB[2][256][64]. Swizzle: phys[r][s] = logical[r][s^(r&7)], s=16B slot.
// Stage plan per iter (T=2i): P1,P2:(T+1)A0,A1 | P3,P4:(T+2)B0,B1 | P5,P6:(T+2)A0,A1 | P7,P8:(T+3)B0,B1
// vmcnt(4) at P4 & P8 (2 loads/phase FIFO) covers every read; slot-free times verified per-phase.
#define BARR() __builtin_amdgcn_s_barrier()
#define LGK0() asm volatile("s_waitcnt lgkmcnt(0)" ::: "memory")
#define VMC4() asm volatile("s_waitcnt vmcnt(4)" ::: "memory")

__global__ __launch_bounds__(512) void head_gemm_8ph(const u16* __restrict__ A,
                                                     const u16* __restrict__ Bw,
                                                     const float* __restrict__ bias,
                                                     float* __restrict__ out){
  __shared__ u16 sA[2][256][64];
  __shared__ u16 sB[2][256][64];
  int t = threadIdx.x, lane = t & 63, w = t >> 6;
  int wm = w >> 2, wn = w & 3;
  int lr = lane & 15, lg = lane >> 4;
  int orig = blockIdx.x;
  int wg = (orig & 7) * (gridDim.x >> 3) + (orig >> 3);  // XCD-chunked (1576 % 8 == 0)
  int m0g = (wg & 7) << 8;                                // m-fastest: B-panel reuse in-XCD
  int n0g = (wg >> 3) << 8;

  int srow = w*8 + (lane >> 3);                  // staging row within half (pass 0)
  int scol = ((lane & 7) ^ (lane >> 3)) * 8;     // pre-swizzled source col (u16)
  const u16* Abase = A  + (size_t)(m0g + srow) * 1024 + scol;
  const u16* Bbase = Bw + (size_t)(n0g + srow) * 1024 + scol;

  f32x4 acc[8][4] = {};
  bf16x8 a[4][2], b0[2][2], b1[2][2];
  int rsw = (lr & 7) << 3;

  auto stA = [&](int buf, int half, int tile){
    const u16* s = Abase + (size_t)half*128*1024 + tile*64;
    gload16(s,           &sA[buf][half*128 +      w*8][0]);
    gload16(s + 64*1024, &sA[buf][half*128 + 64 + w*8][0]);
  };
  auto stB = [&](int buf, int half, int tile){
    const u16* s = Bbase + (size_t)half*128*1024 + tile*64;
    gload16(s,           &sB[buf][half*128 +      w*8][0]);
    gload16(s + 64*1024, &sB[buf][half*128 + 64 + w*8][0]);
  };
  auto rdA = [&](int buf, int half){
    #pragma unroll
    for (int i = 0; i < 4; i++)
      #pragma unroll
      for (int kk = 0; kk < 2; kk++)
        a[i][kk] = *(const bf16x8*)&sA[buf][wm*128 + half*64 + i*16 + lr][(kk*32 + lg*8) ^ rsw];
  };
  auto rdB = [&](int buf, int half, bf16x8 (&bb)[2][2]){
    #pragma unroll
    for (int j = 0; j < 2; j++)
      #pragma unroll
      for (int kk = 0; kk < 2; kk++)
        bb[j][kk] = *(const bf16x8*)&sB[buf][wn*64 + half*32 + j*16 + lr][(kk*32 + lg*8) ^ rsw];
  };
  auto MF = [&](int mb, int nb, bf16x8 (&bb)[2][2]){
    __builtin_amdgcn_s_setprio(1);
    #pragma unroll
    for (int kk = 0; kk < 2; kk++)
      #pragma unroll
      for (int i = 0; i < 4; i++)
        #pragma unroll
        for (int j = 0; j < 2; j++)
          acc[mb+i][nb+j] = __builtin_amdgcn_mfma_f32_16x16x32_bf16(a[i][kk], bb[j][kk], acc[mb+i][nb+j], 0, 0, 0);
    __builtin_amdgcn_s_setprio(0);
  };

  // prologue: tile0 full + tile1 B-halves; wait tile0 landed (allow t1.B in flight)
  stA(0,0,0); stA(0,1,0); stB(0,0,0); stB(0,1,0);
  stB(1,0,1); stB(1,1,1);
  VMC4();
  BARR();

  for (int it = 0; it < 8; ++it){
    int T = it * 2;
    // ---- tile T (buf0) ----
    rdA(0,0); rdB(0,0,b0);                 // P1
    stA(1,0,T+1);
    BARR(); LGK0(); MF(0,0,b0); BARR();
    rdB(0,1,b1);                           // P2
    stA(1,1,T+1);
    BARR(); LGK0(); MF(0,2,b1); BARR();
    rdA(0,1);                              // P3
    if (T+2 < 16) stB(0,0,T+2);
    BARR(); LGK0(); MF(4,2,b1); BARR();
    if (T+2 < 16) stB(0,1,T+2);            // P4
    BARR(); MF(4,0,b0); VMC4(); BARR();
    // ---- tile T+1 (buf1) ----
    rdA(1,0); rdB(1,0,b0);                 // P5
    if (T+2 < 16) stA(0,0,T+2);
    BARR(); LGK0(); MF(0,0,b0); BARR();
    rdB(1,1,b1);                           // P6
    if (T+2 < 16) stA(0,1,T+2);
    BARR(); LGK0(); MF(0,2,b1); BARR();
    rdA(1,1);                              // P7
    if (T+3 < 16) stB(1,0,T+3);
    BARR(); LGK0(); MF(4,2,b1); BARR();
    if (T+3 < 16) stB(1,1,T+3);            // P8
    BARR(); MF(4,0,b0); VMC4(); BARR();
  }

  #pragma unroll
  for (int m = 0; m < 8; m++){
    int gr = m0g + wm*128 + m*16 + lg*4;
    #pragma unroll
    for (int n = 0; n < 4; n++){
      int gc = n0g + wn*64 + n*16 + lr;
      if (gc < Vn){
        float bb = bias[gc];
        #pragma unroll
        for (int r = 0; r < 4; r++)
          out[(size_t)(gr + r) * Vn + gc] = acc[m][n][r] + bb;
      }
    }
  }
}

// ---------------- MFMA fused causal attention (double-buffered K/V, T14 staging) ----------------
__global__ __launch_bounds__(256) void attn_mfma(const u16* __restrict__ qkv,
                                                 const u16* __restrict__ vT,
                                                 float* __restrict__ x){
  int bid = blockIdx.x;
  int bh = bid & 31;
  int j = bid >> 5;
  int qt = (j < 8) ? (15 - j) : (j - 8);
  int b = bh >> 4, h_ = bh & 15;
  int t = threadIdx.x;
  int w = t >> 6, lane = t & 63;
  int lr = lane & 15, lg = lane >> 4;

  __shared__ u16 sK [2][64][72];
  __shared__ u16 sVt[2][64][72];
  __shared__ u16 sP [64][72];

  const u16* qbase = qkv + ((size_t)(b*Tn + qt*64 + w*16 + lr)) * 3*Dm + h_*64 + lg*8;
  bf16x8 qf[2];
  #pragma unroll
  for (int i = 0; i < 2; i++){
    u16x8 raw = *(const u16x8*)(qbase + i * 32);
    #pragma unroll
    for (int u = 0; u < 8; u++) qf[i][u] = (__bf16)(bf2f(raw[u]) * 0.03125f);
  }

  f32x4 o_[4] = {};
  float m_[4], l_[4];
  #pragma unroll
  for (int r = 0; r < 4; r++){ m_[r] = -INFINITY; l_[r] = 0.0f; }

  int sr = t >> 2, scc = (t & 3) * 16;
  const u16* kbase = qkv + ((size_t)(b*Tn + sr)) * 3*Dm + Dm + h_*64 + scc;
  const u16* vbase = vT + ((size_t)(bh*64 + sr)) * Tn + scc;
  int4 kr0, kr1, vr0, vr1;

  kr0 = *(const int4*)(kbase);     kr1 = *(const int4*)(kbase + 8);
  vr0 = *(const int4*)(vbase);     vr1 = *(const int4*)(vbase + 8);
  *(int4*)&sK [0][sr][scc]     = kr0;  *(int4*)&sK [0][sr][scc + 8] = kr1;
  *(int4*)&sVt[0][sr][scc]     = vr0;  *(int4*)&sVt[0][sr][scc + 8] = vr1;

  for (int kt = 0; kt <= qt; kt++){
    int cur = kt & 1;
    if (kt < qt){
      const u16* kb = kbase + (size_t)(kt + 1) * 64 * 3 * Dm;
      const u16* vb = vbase + (kt + 1) * 64;
      kr0 = *(const int4*)(kb);    kr1 = *(const int4*)(kb + 8);
      vr0 = *(const int4*)(vb);    vr1 = *(const int4*)(vb + 8);
    }
    __syncthreads();

    f32x4 s[4] = {};
    __builtin_amdgcn_s_setprio(1);
    #pragma unroll
    for (int kf = 0; kf < 2; kf++){
      #pragma unroll
      for (int nf = 0; nf < 4; nf++){
        bf16x8 kfrag = *(const bf16x8*)&sK[cur][nf*16 + lr][kf*32 + lg*8];
        s[nf] = __builtin_amdgcn_mfma_f32_16x16x32_bf16(qf[kf], kfrag, s[nf], 0, 0, 0);
      }
    }
    __builtin_amdgcn_s_setprio(0);

    bool lastt = (kt == qt);
    float tmax[4] = {-INFINITY, -INFINITY, -INFINITY, -INFINITY};
    #pragma unroll
    for (int nf = 0; nf < 4; nf++)
      #pragma unroll
      for (int r = 0; r < 4; r++){
        float v = s[nf][r];
        if (lastt){
          int kkg = nf*16 + lr, qg = w*16 + lg*4 + r;
          if (kkg > qg) v = -INFINITY;
        }
        s[nf][r] = v;
        tmax[r] = fmaxf(tmax[r], v);
      }
    #pragma unroll
    for (int r = 0; r < 4; r++){
      tmax[r] = fmaxf(tmax[r], __shfl_xor(tmax[r], 1));
      tmax[r] = fmaxf(tmax[r], __shfl_xor(tmax[r], 2));
      tmax[r] = fmaxf(tmax[r], __shfl_xor(tmax[r], 4));
      tmax[r] = fmaxf(tmax[r], __shfl_xor(tmax[r], 8));
    }
    float resc[4], psum[4];
    #pragma unroll
    for (int r = 0; r < 4; r++){
      float nm = fmaxf(m_[r], tmax[r]);
      resc[r] = __expf(m_[r] - nm);
      m_[r] = nm;
      psum[r] = 0.0f;
    }
    #pragma unroll
    for (int nf = 0; nf < 4; nf++)
      #pragma unroll
      for (int r = 0; r < 4; r++){
        float pv = __expf(s[nf][r] - m_[r]);
        s[nf][r] = pv;
        psum[r] += pv;
      }
    #pragma unroll
    for (int r = 0; r < 4; r++){
      psum[r] += __shfl_xor(psum[r], 1);
      psum[r] += __shfl_xor(psum[r], 2);
      psum[r] += __shfl_xor(psum[r], 4);
      psum[r] += __shfl_xor(psum[r], 8);
      l_[r] = l_[r] * resc[r] + psum[r];
    }
    #pragma unroll
    for (int df = 0; df < 4; df++)
      #pragma unroll
      for (int r = 0; r < 4; r++)
        o_[df][r] *= resc[r];

    #pragma unroll
    for (int nf = 0; nf < 4; nf++)
      #pragma unroll
      for (int r = 0; r < 4; r++)
        sP[w*16 + lg*4 + r][nf*16 + lr] = f2bf(s[nf][r]);

    __builtin_amdgcn_s_setprio(1);
    #pragma unroll
    for (int kf = 0; kf < 2; kf++){
      bf16x8 pfrag = *(const bf16x8*)&sP[w*16 + lr][kf*32 + lg*8];
      #pragma unroll
      for (int df = 0; df < 4; df++){
        bf16x8 vfrag = *(const bf16x8*)&sVt[cur][df*16 + lr][kf*32 + lg*8];
        o_[df] = __builtin_amdgcn_mfma_f32_16x16x32_bf16(pfrag, vfrag, o_[df], 0, 0, 0);
      }
    }
    __builtin_amdgcn_s_setprio(0);

    if (kt < qt){
      int nxt = cur ^ 1;
      *(int4*)&sK [nxt][sr][scc]     = kr0;  *(int4*)&sK [nxt][sr][scc + 8] = kr1;
      *(int4*)&sVt[nxt][sr][scc]     = vr0;  *(int4*)&sVt[nxt][sr][scc + 8] = vr1;
    }
  }

  float inv[4];
  #pragma unroll
  for (int r = 0; r < 4; r++) inv[r] = 1.0f / l_[r];
  #pragma unroll
  for (int df = 0; df < 4; df++)
    #pragma unroll
    for (int r = 0; r < 4; r++){
      float* xr = x + ((size_t)(b*Tn + qt*64 + w*16 + lg*4 + r)) * Dm + h_*64 + df*16 + lr;
      *xr += o_[df][r] * inv[r];
    }
}

// ---------------- host orchestration ----------------
extern "C" void kernel_launch(void* const* d_in, const int* in_sizes, int n_in,
                              void* d_out, int out_size, void* d_ws, size_t ws_size,
                              hipStream_t stream){
  const int*   idx   = (const int*)  d_in[0];
  const float* emb   = (const float*)d_in[1];
  const float* pos   = (const float*)d_in[2];
  const float* ln1w  = (const float*)d_in[3];
  const float* ln1b  = (const float*)d_in[4];
  const float* qkvw  = (const float*)d_in[5];
  const float* qkvb  = (const float*)d_in[6];
  const float* ln2w  = (const float*)d_in[7];
  const float* ln2b  = (const float*)d_in[8];
  const float* fc1w  = (const float*)d_in[9];
  const float* fc1b  = (const float*)d_in[10];
  const float* fc2w  = (const float*)d_in[11];
  const float* fc2b  = (const float*)d_in[12];
  const float* lnfw  = (const float*)d_in[13];
  const float* lnfb  = (const float*)d_in[14];
  const float* headw = (const float*)d_in[15];
  const float* headb = (const float*)d_in[16];
  float* out = (float*)d_out;

  const size_t MB = 1u << 20;
  char* ws = (char*)d_ws;
  float* x   = (float*)(ws);                       // 8 MB  [2048][1024] f32
  u16*   h   = (u16*)  (ws + 8*MB);                // 4 MB  [2048][1024] bf16
  u16*   qkv = (u16*)  (ws + 12*MB);               // 12 MB [2048][3072] bf16
  u16*   f1  = (u16*)  (ws + 24*MB);               // 16 MB [2048][4096] bf16

  bool mega    = ws_size >= 320*MB;
  bool bighead = ws_size >= 116*MB;

  u16 *vT, *Bt = nullptr, *BtF = nullptr, *Wq = nullptr, *W1 = nullptr, *W2 = nullptr, *Wh = nullptr;
  if (mega){
    vT = (u16*)(ws + 40*MB);                       // 4 MB
    Wq = (u16*)(ws + 44*MB);                       // 48 MB  (8 x 3072x1024)
    W1 = (u16*)(ws + 92*MB);                       // 64 MB  (8 x 4096x1024)
    W2 = (u16*)(ws + 156*MB);                      // 64 MB  (8 x 1024x4096)
    Wh = (u16*)(ws + 220*MB);                      // 98.5 MiB (50432x1024)
  } else {
    Bt  = (u16*)(ws + 40*MB);
    vT  = (u16*)(ws + 48*MB);
    BtF = (u16*)(ws + 12*MB);
  }

  if (mega)
    mega_transpose<<<35136, 256, 0, stream>>>(qkvw, fc1w, fc2w, headw, Wq, W1, W2, Wh);

  embed_kernel<<<NTOK, 256, 0, stream>>>(idx, emb, pos, x);

  for (int l = 0; l < Ln; l++){
    const u16* Bq = mega ? Wq + (size_t)l*3072*Dm : Bt;
    const u16* B1 = mega ? W1 + (size_t)l*Fm*Dm   : Bt;
    const u16* B2 = mega ? W2 + (size_t)l*Dm*Fm   : Bt;
    // --- attention block ---
    ln_kernel<<<NTOK, 256, 0, stream>>>(x, ln1w + l*Dm, ln1b + l*Dm, h);
    if (!mega) transpose_w<<<dim3(3072/64, Dm/64), 256, 0, stream>>>(qkvw + (size_t)l*Dm*3072, Bt, 3072, Dm, 0);
    gemm_kernel<0, 64,128,1,4,false><<<dim3(3072/128, NTOK/64), 256, 0, stream>>>(h, Bq, qkvb + l*3072, qkv, nullptr, vT, Dm, 3072, 0);
    attn_mfma<<<512, 256, 0, stream>>>(qkv, vT, x);
    // --- MLP block ---
    ln_kernel<<<NTOK, 256, 0, stream>>>(x, ln2w + l*Dm, ln2b + l*Dm, h);
    if (!mega) transpose_w<<<dim3(Fm/64, Dm/64), 256, 0, stream>>>(fc1w + (size_t)l*Dm*Fm, Bt, Fm, Dm, 0);
    gemm_kernel<1,128,128,2,2,false><<<dim3(Fm/128, NTOK/128), 256, 0, stream>>>(h, B1, fc1b + l*Fm, f1, nullptr, nullptr, Dm, Fm, 0);
    if (!mega) transpose_w<<<dim3(Dm/64, Fm/64), 256, 0, stream>>>(fc2w + (size_t)l*Fm*Dm, Bt, Dm, Fm, 0);
    gemm_kernel<2, 64,128,1,4,false><<<dim3(Dm/128, NTOK/64), 256, 0, stream>>>(f1, B2, fc2b + l*Dm, nullptr, x, nullptr, Fm, Dm, 0);
  }

  ln_kernel<<<NTOK, 256, 0, stream>>>(x, lnfw, lnfb, h);

  if (mega){
    head_gemm_8ph<<<1576, 512, 0, stream>>>(h, Wh, headb, out);    // 8 m x 197 n tiles
  } else if (bighead){
    transpose_w<<<dim3(786, Dm/64), 256, 0, stream>>>(headw, BtF, Vn, Dm, 0);
    gemm_kernel<3,128,128,2,2,true><<<6288, 256, 0, stream>>>(h, BtF, headb, out, nullptr, nullptr, Dm, Vn, 0);
  } else {
    const int CHUNK = 4096;
    for (int c0 = 0; c0 < Vn; c0 += CHUNK){
      int W = Vn - c0; if (W > CHUNK) W = CHUNK;
      int ngx = (W + 127) / 128;
      transpose_w<<<dim3(ngx * 2, Dm/64), 256, 0, stream>>>(headw, Bt, Vn, Dm, c0);
      gemm_kernel<3,128,128,2,2,false><<<dim3(ngx, NTOK/128), 256, 0, stream>>>(h, Bt, headb, out, nullptr, nullptr, Dm, Vn, c0);
    }
  }
}